// Round 1
// baseline (617.266 us; speedup 1.0000x reference)
//
#include <hip/hip_runtime.h>
#include <math.h>

typedef __bf16 bf16;
typedef bf16 bf16x8 __attribute__((ext_vector_type(8)));
typedef bf16 bf16x4 __attribute__((ext_vector_type(4)));
typedef float f32x4 __attribute__((ext_vector_type(4)));

#define MFMA(a, b, c) __builtin_amdgcn_mfma_f32_16x16x32_bf16((a), (b), (c), 0, 0, 0)

// ---------------- workspace layout (bf16 element offsets) ----------------
static const size_t E_WT_ATTN = 0;          // [3072][1024]
static const size_t E_WT_PROJ = 3145728;    // [1024][1024]
static const size_t E_WT_MLP1 = 4194304;    // [4096][1024]
static const size_t E_WT_MLP2 = 8388608;    // [1024][4096]
static const size_t E_LN1     = 12582912;   // [4096][1024]
static const size_t E_QKV     = 16777216;   // [4096][3072]
static const size_t E_Q       = 29360128;   // [B,H,T,64]
static const size_t E_K       = 33554432;   // [B,H,T,64]
static const size_t E_VT      = 37748736;   // [B,H,64,T]
static const size_t E_Y       = 41943040;   // [4096][1024]
static const size_t E_LN2     = 46137344;   // [4096][1024]
static const size_t E_H       = 50331648;   // [4096][4096]
static const size_t BYTE_X2   = 134217728;  // float [4096][1024]
static const size_t TOTAL_BYTES = 150994944;

__device__ __align__(4096) unsigned char g_buf[TOTAL_BYTES];

// ---------------- transpose + cast: in f32 [K][N] -> out bf16 [N][K] ----------------
__global__ __launch_bounds__(256) void transpose_cast(const float* __restrict__ in,
                                                      bf16* __restrict__ out, int K, int N) {
  __shared__ float tile[32][33];
  int bx = blockIdx.x, by = blockIdx.y;
  int tx = threadIdx.x, ty = threadIdx.y;
#pragma unroll
  for (int i = ty; i < 32; i += 8)
    tile[i][tx] = in[(size_t)(by * 32 + i) * N + bx * 32 + tx];
  __syncthreads();
#pragma unroll
  for (int i = ty; i < 32; i += 8)
    out[(size_t)(bx * 32 + i) * K + by * 32 + tx] = (bf16)tile[tx][i];
}

// ---------------- LayerNorm f32 row(1024) -> bf16 ----------------
__global__ __launch_bounds__(256) void ln_bf16(const float* __restrict__ x,
                                               const float* __restrict__ g,
                                               const float* __restrict__ b,
                                               bf16* __restrict__ out) {
  int row = blockIdx.x, tid = threadIdx.x;
  const float* xr = x + ((size_t)row << 10);
  float4 v = *(const float4*)(xr + tid * 4);
  float s = v.x + v.y + v.z + v.w;
  float ss = v.x * v.x + v.y * v.y + v.z * v.z + v.w * v.w;
#pragma unroll
  for (int off = 32; off >= 1; off >>= 1) {
    s += __shfl_down(s, off);
    ss += __shfl_down(ss, off);
  }
  __shared__ float sh[8];
  int wid = tid >> 6;
  if ((tid & 63) == 0) { sh[wid] = s; sh[wid + 4] = ss; }
  __syncthreads();
  float ts = sh[0] + sh[1] + sh[2] + sh[3];
  float tss = sh[4] + sh[5] + sh[6] + sh[7];
  float mean = ts * (1.0f / 1024.0f);
  float var = tss * (1.0f / 1024.0f) - mean * mean;
  float inv = rsqrtf(var + 1e-5f);
  float4 gg = *(const float4*)(g + tid * 4);
  float4 bb = *(const float4*)(b + tid * 4);
  bf16x4 o;
  o[0] = (bf16)((v.x - mean) * inv * gg.x + bb.x);
  o[1] = (bf16)((v.y - mean) * inv * gg.y + bb.y);
  o[2] = (bf16)((v.z - mean) * inv * gg.z + bb.z);
  o[3] = (bf16)((v.w - mean) * inv * gg.w + bb.w);
  *(bf16x4*)(out + ((size_t)row << 10) + tid * 4) = o;
}

// ---------------- GEMM: C[M][N] = A[M][K](bf16) @ Bt[N][K](bf16)^T + bias ----------------
// EPI 0: outb = bf16(acc+bias)
// EPI 1: outb = bf16(gelu(acc+bias))
// EPI 2: outf = res*wsc + acc + bias
template <int EPI>
__global__ __launch_bounds__(256) void gemm_bt(const bf16* __restrict__ A,
                                               const bf16* __restrict__ Bt,
                                               const float* __restrict__ bias,
                                               bf16* __restrict__ outb,
                                               float* __restrict__ outf,
                                               const float* __restrict__ res,
                                               const float* __restrict__ wsc,
                                               int M, int N, int K) {
  __shared__ bf16 As[128 * 40];
  __shared__ bf16 Bs[128 * 40];
  int bx = blockIdx.x, by = blockIdx.y;
  int tid = threadIdx.x;
  int lane = tid & 63, wid = tid >> 6;
  int wr = wid >> 1, wc = wid & 1;
  int g = lane >> 4, lr = lane & 15;
  f32x4 acc[4][4];
#pragma unroll
  for (int m = 0; m < 4; ++m)
#pragma unroll
    for (int n = 0; n < 4; ++n) acc[m][n] = (f32x4){0.f, 0.f, 0.f, 0.f};
  const bf16* Ab = A + (size_t)by * 128 * K;
  const bf16* Bb = Bt + (size_t)bx * 128 * K;
  int srow = tid >> 2;
  int skc = (tid & 3) * 8;
  for (int k0 = 0; k0 < K; k0 += 32) {
#pragma unroll
    for (int p = 0; p < 2; ++p) {
      int r = p * 64 + srow;
      *(uint4*)(&As[r * 40 + skc]) = *(const uint4*)(Ab + (size_t)r * K + k0 + skc);
      *(uint4*)(&Bs[r * 40 + skc]) = *(const uint4*)(Bb + (size_t)r * K + k0 + skc);
    }
    __syncthreads();
    bf16x8 af[4], bfr[4];
#pragma unroll
    for (int m = 0; m < 4; ++m) af[m] = *(const bf16x8*)(&As[(wr * 64 + m * 16 + lr) * 40 + g * 8]);
#pragma unroll
    for (int n = 0; n < 4; ++n) bfr[n] = *(const bf16x8*)(&Bs[(wc * 64 + n * 16 + lr) * 40 + g * 8]);
#pragma unroll
    for (int m = 0; m < 4; ++m)
#pragma unroll
      for (int n = 0; n < 4; ++n) acc[m][n] = MFMA(af[m], bfr[n], acc[m][n]);
    __syncthreads();
  }
  const float w = (EPI == 2) ? wsc[0] : 0.f;
#pragma unroll
  for (int m = 0; m < 4; ++m) {
#pragma unroll
    for (int n = 0; n < 4; ++n) {
      int rg0 = by * 128 + wr * 64 + m * 16 + g * 4;
      int cg = bx * 128 + wc * 64 + n * 16 + lr;
      float bv = bias[cg];
#pragma unroll
      for (int j = 0; j < 4; ++j) {
        float v = acc[m][n][j] + bv;
        size_t idx = (size_t)(rg0 + j) * N + cg;
        if (EPI == 0)
          outb[idx] = (bf16)v;
        else if (EPI == 1)
          outb[idx] = (bf16)(0.5f * v * (1.0f + erff(v * 0.70710678118f)));
        else
          outf[idx] = res[idx] * w + v;
      }
    }
  }
}

// ---------------- qkv split ----------------
__global__ __launch_bounds__(256) void split_qk(const bf16* __restrict__ qkv,
                                                bf16* __restrict__ q, bf16* __restrict__ k) {
  size_t i = (size_t)blockIdx.x * 256 + threadIdx.x;  // over 4096*1024
  int row = (int)(i >> 10);
  int e = (int)(i & 1023);
  int b = row >> 11, t = row & 2047;
  int h = e >> 6, d = e & 63;
  size_t src = (size_t)row * 3072;
  size_t dst = (((size_t)(b * 16 + h) * 2048) + t) * 64 + d;
  q[dst] = qkv[src + e];
  k[dst] = qkv[src + 1024 + e];
}

__global__ __launch_bounds__(256) void split_v_t(const bf16* __restrict__ qkv,
                                                 bf16* __restrict__ vT) {
  int t0 = blockIdx.x * 32;
  int bh = blockIdx.y;
  int b = bh >> 4, h = bh & 15;
  __shared__ bf16 tile[32][72];
  int tid = threadIdx.x;
  int d = tid & 63, tl0 = tid >> 6;  // tl0: 0..3
#pragma unroll
  for (int p = 0; p < 8; ++p) {
    int tl = p * 4 + tl0;
    tile[tl][d] = qkv[((size_t)(b * 2048 + t0 + tl)) * 3072 + 2048 + h * 64 + d];
  }
  __syncthreads();
  int tl = tid & 31, dq = tid >> 5;  // dq: 0..7
#pragma unroll
  for (int p = 0; p < 8; ++p) {
    int dd = p * 8 + dq;
    vT[((size_t)(bh * 64 + dd)) * 2048 + t0 + tl] = tile[tl][dd];
  }
}

// ---------------- flash attention fwd ----------------
// q,k: [B,H,T,64] bf16; vT: [B,H,64,T] bf16; y: [B,T,E] bf16 (E index = h*64+d)
__global__ __launch_bounds__(256) void attn_fwd(const bf16* __restrict__ q,
                                                const bf16* __restrict__ k,
                                                const bf16* __restrict__ vT,
                                                bf16* __restrict__ y) {
  int qi = blockIdx.x;
  int bh = blockIdx.y;
  int b = bh >> 4, h = bh & 15;
  int tid = threadIdx.x, wid = tid >> 6, lane = tid & 63;
  int g = lane >> 4, lr = lane & 15;
  const bf16* Q = q + (size_t)bh * 2048 * 64;
  const bf16* Kp = k + (size_t)bh * 2048 * 64;
  const bf16* Vp = vT + (size_t)bh * 64 * 2048;
  int qrow0 = qi * 64 + wid * 16;
  bf16x8 qf[2];
#pragma unroll
  for (int kk = 0; kk < 2; ++kk)
    qf[kk] = *(const bf16x8*)(Q + (size_t)(qrow0 + lr) * 64 + kk * 32 + g * 8);
  f32x4 o[4];
#pragma unroll
  for (int n = 0; n < 4; ++n) o[n] = (f32x4){0.f, 0.f, 0.f, 0.f};
  float m[4] = {-3e38f, -3e38f, -3e38f, -3e38f};
  float l[4] = {0.f, 0.f, 0.f, 0.f};
  __shared__ bf16 P[4][16][72];
  for (int kt = 0; kt <= qi; ++kt) {
    f32x4 s[4];
#pragma unroll
    for (int n = 0; n < 4; ++n) s[n] = (f32x4){0.f, 0.f, 0.f, 0.f};
#pragma unroll
    for (int kk = 0; kk < 2; ++kk) {
#pragma unroll
      for (int n = 0; n < 4; ++n) {
        bf16x8 kf = *(const bf16x8*)(Kp + (size_t)(kt * 64 + n * 16 + lr) * 64 + kk * 32 + g * 8);
        s[n] = MFMA(qf[kk], kf, s[n]);
      }
    }
#pragma unroll
    for (int n = 0; n < 4; ++n) {
      int col = kt * 64 + n * 16 + lr;
#pragma unroll
      for (int j = 0; j < 4; ++j) {
        int row = qrow0 + g * 4 + j;
        float sv = s[n][j] * 0.125f;
        s[n][j] = (col <= row) ? sv : -3e38f;
      }
    }
#pragma unroll
    for (int j = 0; j < 4; ++j) {
      float rmax = fmaxf(fmaxf(s[0][j], s[1][j]), fmaxf(s[2][j], s[3][j]));
#pragma unroll
      for (int off = 8; off >= 1; off >>= 1) rmax = fmaxf(rmax, __shfl_xor(rmax, off));
      float mn = fmaxf(m[j], rmax);
      float al = expf(m[j] - mn);
      m[j] = mn;
      float rs = 0.f;
#pragma unroll
      for (int n = 0; n < 4; ++n) {
        float p = expf(s[n][j] - mn);
        s[n][j] = p;
        rs += p;
      }
#pragma unroll
      for (int off = 8; off >= 1; off >>= 1) rs += __shfl_xor(rs, off);
      l[j] = l[j] * al + rs;
#pragma unroll
      for (int n = 0; n < 4; ++n) o[n][j] *= al;
    }
#pragma unroll
    for (int n = 0; n < 4; ++n)
#pragma unroll
      for (int j = 0; j < 4; ++j) P[wid][g * 4 + j][n * 16 + lr] = (bf16)s[n][j];
#pragma unroll
    for (int kk = 0; kk < 2; ++kk) {
      bf16x8 pf = *(const bf16x8*)(&P[wid][lr][kk * 32 + g * 8]);
#pragma unroll
      for (int n = 0; n < 4; ++n) {
        bf16x8 vf = *(const bf16x8*)(Vp + (size_t)(n * 16 + lr) * 2048 + kt * 64 + kk * 32 + g * 8);
        o[n] = MFMA(pf, vf, o[n]);
      }
    }
  }
#pragma unroll
  for (int j = 0; j < 4; ++j) {
    float inv = 1.0f / l[j];
    int t = qrow0 + g * 4 + j;
#pragma unroll
    for (int n = 0; n < 4; ++n)
      y[((size_t)b * 2048 + t) * 1024 + h * 64 + n * 16 + lr] = (bf16)(o[n][j] * inv);
  }
}

// ---------------- launch ----------------
extern "C" void kernel_launch(void* const* d_in, const int* in_sizes, int n_in,
                              void* d_out, int out_size, void* d_ws, size_t ws_size,
                              hipStream_t stream) {
  const float* x = (const float*)d_in[0];
  const float* ln1_g = (const float*)d_in[1];
  const float* ln1_b = (const float*)d_in[2];
  const float* attn_w = (const float*)d_in[3];
  const float* attn_b = (const float*)d_in[4];
  const float* proj_w = (const float*)d_in[5];
  const float* proj_b = (const float*)d_in[6];
  const float* ln2_g = (const float*)d_in[7];
  const float* ln2_b = (const float*)d_in[8];
  const float* mlp_w1 = (const float*)d_in[9];
  const float* mlp_b1 = (const float*)d_in[10];
  const float* mlp_w2 = (const float*)d_in[11];
  const float* mlp_b2 = (const float*)d_in[12];
  const float* w_att = (const float*)d_in[13];
  const float* w_mlp = (const float*)d_in[14];
  float* out = (float*)d_out;

  unsigned char* base = nullptr;
  if (ws_size >= TOTAL_BYTES) {
    base = (unsigned char*)d_ws;
  } else {
    hipGetSymbolAddress((void**)&base, HIP_SYMBOL(g_buf));
  }
  bf16* bb = (bf16*)base;
  bf16* wt_attn = bb + E_WT_ATTN;
  bf16* wt_proj = bb + E_WT_PROJ;
  bf16* wt_mlp1 = bb + E_WT_MLP1;
  bf16* wt_mlp2 = bb + E_WT_MLP2;
  bf16* ln1o = bb + E_LN1;
  bf16* qkv = bb + E_QKV;
  bf16* qb = bb + E_Q;
  bf16* kb = bb + E_K;
  bf16* vTb = bb + E_VT;
  bf16* yb = bb + E_Y;
  bf16* ln2o = bb + E_LN2;
  bf16* hb = bb + E_H;
  float* x2 = (float*)(base + BYTE_X2);

  dim3 tb(32, 8);
  transpose_cast<<<dim3(3072 / 32, 1024 / 32), tb, 0, stream>>>(attn_w, wt_attn, 1024, 3072);
  transpose_cast<<<dim3(1024 / 32, 1024 / 32), tb, 0, stream>>>(proj_w, wt_proj, 1024, 1024);
  transpose_cast<<<dim3(4096 / 32, 1024 / 32), tb, 0, stream>>>(mlp_w1, wt_mlp1, 1024, 4096);
  transpose_cast<<<dim3(1024 / 32, 4096 / 32), tb, 0, stream>>>(mlp_w2, wt_mlp2, 4096, 1024);

  ln_bf16<<<4096, 256, 0, stream>>>(x, ln1_g, ln1_b, ln1o);

  gemm_bt<0><<<dim3(3072 / 128, 4096 / 128), 256, 0, stream>>>(
      ln1o, wt_attn, attn_b, qkv, nullptr, nullptr, nullptr, 4096, 3072, 1024);

  split_qk<<<16384, 256, 0, stream>>>(qkv, qb, kb);
  split_v_t<<<dim3(64, 32), 256, 0, stream>>>(qkv, vTb);

  attn_fwd<<<dim3(32, 32), 256, 0, stream>>>(qb, kb, vTb, yb);

  gemm_bt<2><<<dim3(1024 / 128, 4096 / 128), 256, 0, stream>>>(
      yb, wt_proj, proj_b, nullptr, x2, x, w_att, 4096, 1024, 1024);

  ln_bf16<<<4096, 256, 0, stream>>>(x2, ln2_g, ln2_b, ln2o);

  gemm_bt<1><<<dim3(4096 / 128, 4096 / 128), 256, 0, stream>>>(
      ln2o, wt_mlp1, mlp_b1, hb, nullptr, nullptr, nullptr, 4096, 4096, 1024);

  gemm_bt<2><<<dim3(1024 / 128, 4096 / 128), 256, 0, stream>>>(
      hb, wt_mlp2, mlp_b2, nullptr, out, x2, w_mlp, 4096, 1024, 4096);
}

// Round 3
// 552.343 us; speedup vs baseline: 1.1175x; 1.1175x over previous
//
#include <hip/hip_runtime.h>
#include <math.h>

typedef __bf16 bf16;
typedef bf16 bf16x8 __attribute__((ext_vector_type(8)));
typedef bf16 bf16x4 __attribute__((ext_vector_type(4)));
typedef float f32x4 __attribute__((ext_vector_type(4)));

#define MFMA(a, b, c) __builtin_amdgcn_mfma_f32_16x16x32_bf16((a), (b), (c), 0, 0, 0)

#define GLOAD_LDS16(gp, lp)                                                        \
  __builtin_amdgcn_global_load_lds((const __attribute__((address_space(1))) void*)(gp), \
                                   (__attribute__((address_space(3))) void*)(lp), 16, 0, 0)

// ---------------- workspace layout ----------------
// bf16 element offsets
static const size_t E_WT_ATTN = 0;          // [3072][1024]
static const size_t E_WT_PROJ = 3145728;    // [1024][1024]
static const size_t E_WT_MLP1 = 4194304;    // [4096][1024]
static const size_t E_WT_MLP2 = 8388608;    // [1024][4096]
static const size_t E_LN1     = 12582912;   // [4096][1024]
static const size_t E_QKV     = 16777216;   // [4096][3072]
static const size_t E_Q       = 29360128;   // [B,H,T,64]
static const size_t E_K       = 33554432;   // [B,H,T,64]
static const size_t E_VT      = 37748736;   // [B,H,64,T]
static const size_t E_Y       = 41943040;   // [4096][1024]
static const size_t E_LN2     = 46137344;   // [4096][1024]
static const size_t E_H       = 50331648;   // [4096][4096]
// byte offsets
static const size_t BYTE_X2    = 134217728; // float [4096][1024]
static const size_t BYTE_OPART = 150994944; // float [2048][64][64] attn partials
static const size_t BYTE_ML    = 184549376; // float [2048][64][2]
static const size_t BYTE_GPART = 185597952; // float [4][4096][1024] gemm split-K partials
static const size_t TOTAL_BYTES = 252706816;

__device__ __align__(4096) unsigned char g_buf[TOTAL_BYTES];

// ---------------- transpose + cast: in f32 [K][N] -> out bf16 [N][K] ----------------
__global__ __launch_bounds__(256) void transpose_cast(const float* __restrict__ in,
                                                      bf16* __restrict__ out, int K, int N) {
  __shared__ float tile[32][33];
  int bx = blockIdx.x, by = blockIdx.y;
  int tx = threadIdx.x, ty = threadIdx.y;
#pragma unroll
  for (int i = ty; i < 32; i += 8)
    tile[i][tx] = in[(size_t)(by * 32 + i) * N + bx * 32 + tx];
  __syncthreads();
#pragma unroll
  for (int i = ty; i < 32; i += 8)
    out[(size_t)(bx * 32 + i) * K + by * 32 + tx] = (bf16)tile[tx][i];
}

// ---------------- LayerNorm f32 row(1024) -> bf16 ----------------
__global__ __launch_bounds__(256) void ln_bf16(const float* __restrict__ x,
                                               const float* __restrict__ g,
                                               const float* __restrict__ b,
                                               bf16* __restrict__ out) {
  int row = blockIdx.x, tid = threadIdx.x;
  const float* xr = x + ((size_t)row << 10);
  float4 v = *(const float4*)(xr + tid * 4);
  float s = v.x + v.y + v.z + v.w;
  float ss = v.x * v.x + v.y * v.y + v.z * v.z + v.w * v.w;
#pragma unroll
  for (int off = 32; off >= 1; off >>= 1) {
    s += __shfl_down(s, off);
    ss += __shfl_down(ss, off);
  }
  __shared__ float sh[8];
  int wid = tid >> 6;
  if ((tid & 63) == 0) { sh[wid] = s; sh[wid + 4] = ss; }
  __syncthreads();
  float ts = sh[0] + sh[1] + sh[2] + sh[3];
  float tss = sh[4] + sh[5] + sh[6] + sh[7];
  float mean = ts * (1.0f / 1024.0f);
  float var = tss * (1.0f / 1024.0f) - mean * mean;
  float inv = rsqrtf(var + 1e-5f);
  float4 gg = *(const float4*)(g + tid * 4);
  float4 bb = *(const float4*)(b + tid * 4);
  bf16x4 o;
  o[0] = (bf16)((v.x - mean) * inv * gg.x + bb.x);
  o[1] = (bf16)((v.y - mean) * inv * gg.y + bb.y);
  o[2] = (bf16)((v.z - mean) * inv * gg.z + bb.z);
  o[3] = (bf16)((v.w - mean) * inv * gg.w + bb.w);
  *(bf16x4*)(out + ((size_t)row << 10) + tid * 4) = o;
}

// ---------------- GEMM: C[M][N] = A[M][K](bf16) @ Bt[N][K]^T ----------------
// EPI 0: outb = bf16(acc+bias); EPI 1: outb = bf16(gelu(acc+bias));
// EPI 3: outf[z*M*N + idx] = acc (split-K partial, no bias)
template <int EPI>
__global__ __launch_bounds__(256) void gemm_bt(const bf16* __restrict__ A,
                                               const bf16* __restrict__ Bt,
                                               const float* __restrict__ bias,
                                               bf16* __restrict__ outb,
                                               float* __restrict__ outf,
                                               int M, int N, int K, int Kseg) {
  __shared__ __align__(16) bf16 As[128 * 32];
  __shared__ __align__(16) bf16 Bs[128 * 32];
  int bx = blockIdx.x, by = blockIdx.y;
  int tid = threadIdx.x;
  int lane = tid & 63, wid = tid >> 6;
  int wr = wid >> 1, wc = wid & 1;
  int g = lane >> 4, lr = lane & 15;
  f32x4 acc[4][4];
#pragma unroll
  for (int m = 0; m < 4; ++m)
#pragma unroll
    for (int n = 0; n < 4; ++n) acc[m][n] = (f32x4){0.f, 0.f, 0.f, 0.f};
  const bf16* Ab = A + (size_t)by * 128 * K;
  const bf16* Bb = Bt + (size_t)bx * 128 * K;
  int srow = tid >> 2;
  int sk8 = (tid & 3) * 8;
  const bf16* Ap0 = Ab + (size_t)srow * K + sk8;
  const bf16* Ap1 = Ab + (size_t)(srow + 64) * K + sk8;
  const bf16* Bp0 = Bb + (size_t)srow * K + sk8;
  const bf16* Bp1 = Bb + (size_t)(srow + 64) * K + sk8;
  bf16* lA0 = As + tid * 8;
  bf16* lA1 = As + 2048 + tid * 8;
  bf16* lB0 = Bs + tid * 8;
  bf16* lB1 = Bs + 2048 + tid * 8;
  int kbeg = blockIdx.z * Kseg;
  int kend = kbeg + Kseg;
  for (int k0 = kbeg; k0 < kend; k0 += 32) {
    GLOAD_LDS16(Ap0 + k0, lA0);
    GLOAD_LDS16(Ap1 + k0, lA1);
    GLOAD_LDS16(Bp0 + k0, lB0);
    GLOAD_LDS16(Bp1 + k0, lB1);
    __syncthreads();
    bf16x8 af[4], bfv[4];
#pragma unroll
    for (int m = 0; m < 4; ++m) af[m] = *(const bf16x8*)(As + (wr * 64 + m * 16 + lr) * 32 + g * 8);
#pragma unroll
    for (int n = 0; n < 4; ++n) bfv[n] = *(const bf16x8*)(Bs + (wc * 64 + n * 16 + lr) * 32 + g * 8);
#pragma unroll
    for (int m = 0; m < 4; ++m)
#pragma unroll
      for (int n = 0; n < 4; ++n) acc[m][n] = MFMA(af[m], bfv[n], acc[m][n]);
    __syncthreads();
  }
  if (EPI == 3) {
    float* po = outf + (size_t)blockIdx.z * M * N;
#pragma unroll
    for (int m = 0; m < 4; ++m) {
#pragma unroll
      for (int n = 0; n < 4; ++n) {
        int rg0 = by * 128 + wr * 64 + m * 16 + g * 4;
        int cg = bx * 128 + wc * 64 + n * 16 + lr;
#pragma unroll
        for (int j = 0; j < 4; ++j) po[(size_t)(rg0 + j) * N + cg] = acc[m][n][j];
      }
    }
  } else {
#pragma unroll
    for (int m = 0; m < 4; ++m) {
#pragma unroll
      for (int n = 0; n < 4; ++n) {
        int rg0 = by * 128 + wr * 64 + m * 16 + g * 4;
        int cg = bx * 128 + wc * 64 + n * 16 + lr;
        float bv = bias[cg];
#pragma unroll
        for (int j = 0; j < 4; ++j) {
          float v = acc[m][n][j] + bv;
          size_t idx = (size_t)(rg0 + j) * N + cg;
          if (EPI == 0)
            outb[idx] = (bf16)v;
          else
            outb[idx] = (bf16)(0.5f * v * (1.0f + erff(v * 0.70710678118f)));
        }
      }
    }
  }
}

// ---------------- split-K reduce: out = res*w + sum(parts) + bias ----------------
template <int SK>
__global__ __launch_bounds__(256) void reduce_add(const float* __restrict__ part,
                                                  const float* __restrict__ bias,
                                                  const float* __restrict__ res,
                                                  const float* __restrict__ wsc,
                                                  float* __restrict__ out, int MN, int N) {
  size_t i = ((size_t)blockIdx.x * 256 + threadIdx.x) * 4;
  float4 a = *(const float4*)(part + i);
#pragma unroll
  for (int s = 1; s < SK; ++s) {
    float4 b = *(const float4*)(part + (size_t)s * MN + i);
    a.x += b.x; a.y += b.y; a.z += b.z; a.w += b.w;
  }
  int col = (int)(i & (size_t)(N - 1));
  float4 bv = *(const float4*)(bias + col);
  float4 rv = *(const float4*)(res + i);
  float w = wsc[0];
  float4 o;
  o.x = rv.x * w + a.x + bv.x;
  o.y = rv.y * w + a.y + bv.y;
  o.z = rv.z * w + a.z + bv.z;
  o.w = rv.w * w + a.w + bv.w;
  *(float4*)(out + i) = o;
}

// ---------------- qkv split (vectorized) ----------------
__global__ __launch_bounds__(256) void split_qk(const bf16* __restrict__ qkv,
                                                bf16* __restrict__ q, bf16* __restrict__ k) {
  size_t i = (size_t)blockIdx.x * 256 + threadIdx.x;  // over 4096*128
  int row = (int)(i >> 7);
  int e = (int)(i & 127) << 3;
  int b = row >> 11, t = row & 2047;
  int h = e >> 6, d = e & 63;
  const bf16* src = qkv + (size_t)row * 3072;
  size_t dst = (((size_t)((b << 4) + h) * 2048) + t) * 64 + d;
  *(bf16x8*)(q + dst) = *(const bf16x8*)(src + e);
  *(bf16x8*)(k + dst) = *(const bf16x8*)(src + 1024 + e);
}

__global__ __launch_bounds__(256) void split_v_t(const bf16* __restrict__ qkv,
                                                 bf16* __restrict__ vT) {
  int t0 = blockIdx.x * 32;
  int bh = blockIdx.y;
  int b = bh >> 4, h = bh & 15;
  __shared__ bf16 tile[32][72];
  int tid = threadIdx.x;
  int d = tid & 63, tl0 = tid >> 6;
#pragma unroll
  for (int p = 0; p < 8; ++p) {
    int tl = p * 4 + tl0;
    tile[tl][d] = qkv[((size_t)(b * 2048 + t0 + tl)) * 3072 + 2048 + h * 64 + d];
  }
  __syncthreads();
  int tl = tid & 31, dq = tid >> 5;
#pragma unroll
  for (int p = 0; p < 8; ++p) {
    int dd = p * 8 + dq;
    vT[((size_t)(bh * 64 + dd)) * 2048 + t0 + tl] = tile[tl][dd];
  }
}

// ---------------- flash attention fwd (swapped QK^T, split-K=2) ----------------
// q,k: [B,H,T,64]; vT: [B,H,64,T]; partials: o_part [2048][64][64] f32, ml [2048][64][2]
__global__ __launch_bounds__(256) void attn_fwd(const bf16* __restrict__ q,
                                                const bf16* __restrict__ k,
                                                const bf16* __restrict__ vT,
                                                float* __restrict__ o_part,
                                                float* __restrict__ ml_part) {
  int id = blockIdx.x;            // 0..2047
  int bh = id & 31;
  int seg = (id >> 5) & 1;
  int qi = ((id >> 6) + bh) & 31; // stagger causal depth across consecutive ids
  int tid = threadIdx.x, wid = tid >> 6, lane = tid & 63;
  int g = lane >> 4, lr = lane & 15;
  const bf16* Q = q + (size_t)bh * (2048 * 64);
  const bf16* Kp = k + (size_t)bh * (2048 * 64);
  const bf16* Vp = vT + (size_t)bh * (64 * 2048);
  int nk = qi + 1;
  int n0 = (nk + 1) >> 1;
  int kt0 = seg ? n0 : 0;
  int kt1 = seg ? nk : n0;
  int qrow = qi * 64 + wid * 16 + lr;
  bf16x8 qf[2];
  qf[0] = *(const bf16x8*)(Q + (size_t)qrow * 64 + g * 8);
  qf[1] = *(const bf16x8*)(Q + (size_t)qrow * 64 + 32 + g * 8);
  f32x4 o[4];
#pragma unroll
  for (int n = 0; n < 4; ++n) o[n] = (f32x4){0.f, 0.f, 0.f, 0.f};
  float m = -3e38f, l = 0.f;
  __shared__ bf16 P[4][16][72];
  for (int kt = kt0; kt < kt1; ++kt) {
    const bf16* Kt = Kp + (size_t)kt * 64 * 64;
    f32x4 s[4];
#pragma unroll
    for (int n = 0; n < 4; ++n) s[n] = (f32x4){0.f, 0.f, 0.f, 0.f};
#pragma unroll
    for (int kk = 0; kk < 2; ++kk) {
#pragma unroll
      for (int n = 0; n < 4; ++n) {
        bf16x8 kf = *(const bf16x8*)(Kt + (size_t)(n * 16 + lr) * 64 + kk * 32 + g * 8);
        s[n] = MFMA(kf, qf[kk], s[n]);   // S^T: lane holds row qrow=lr, kcols n*16+g*4+j
      }
    }
    int kc0 = kt * 64 + g * 4;
#pragma unroll
    for (int n = 0; n < 4; ++n)
#pragma unroll
      for (int j = 0; j < 4; ++j) {
        float sv = s[n][j] * 0.125f;
        s[n][j] = ((kc0 + n * 16 + j) <= qrow) ? sv : -3e38f;
      }
    // row max: in-lane 16 then across the 4 g-groups
    float mx = s[0][0];
#pragma unroll
    for (int n = 0; n < 4; ++n)
#pragma unroll
      for (int j = 0; j < 4; ++j) mx = fmaxf(mx, s[n][j]);
    mx = fmaxf(mx, __shfl_xor(mx, 16));
    mx = fmaxf(mx, __shfl_xor(mx, 32));
    float mn = fmaxf(m, mx);
    float al = __expf(m - mn);
    m = mn;
    float rs = 0.f;
    bf16x4 pw[4];
#pragma unroll
    for (int n = 0; n < 4; ++n)
#pragma unroll
      for (int j = 0; j < 4; ++j) {
        float p = __expf(s[n][j] - mn);
        rs += p;
        pw[n][j] = (bf16)p;
      }
    rs += __shfl_xor(rs, 16);
    rs += __shfl_xor(rs, 32);
    l = l * al + rs;
    // broadcast al to the lanes holding output rows g*4+j
    int sb = (lane & 48) | ((lane >> 4) << 2);
    float alj[4];
#pragma unroll
    for (int j = 0; j < 4; ++j) alj[j] = __shfl(al, sb + j);
#pragma unroll
    for (int n = 0; n < 4; ++n)
#pragma unroll
      for (int j = 0; j < 4; ++j) o[n][j] *= alj[j];
    // stash P rows to LDS (wave-private slice), re-read as PV A-fragments
#pragma unroll
    for (int n = 0; n < 4; ++n) *(bf16x4*)&P[wid][lr][n * 16 + g * 4] = pw[n];
#pragma unroll
    for (int kk = 0; kk < 2; ++kk) {
      bf16x8 pf = *(const bf16x8*)&P[wid][lr][kk * 32 + g * 8];
#pragma unroll
      for (int n = 0; n < 4; ++n) {
        bf16x8 vf = *(const bf16x8*)(Vp + (size_t)(n * 16 + lr) * 2048 + kt * 64 + kk * 32 + g * 8);
        o[n] = MFMA(pf, vf, o[n]);
      }
    }
  }
  float* ob = o_part + (size_t)id * 4096;
#pragma unroll
  for (int n = 0; n < 4; ++n)
#pragma unroll
    for (int j = 0; j < 4; ++j)
      ob[(size_t)(wid * 16 + g * 4 + j) * 64 + n * 16 + lr] = o[n][j];
  if (lane < 16) {
    ml_part[(size_t)id * 128 + (wid * 16 + lane) * 2] = m;
    ml_part[(size_t)id * 128 + (wid * 16 + lane) * 2 + 1] = l;
  }
}

// ---------------- attention combine: merge 2 segments, normalize, write y ----------------
__global__ __launch_bounds__(256) void attn_combine(const float* __restrict__ o_part,
                                                    const float* __restrict__ ml_part,
                                                    bf16* __restrict__ y) {
  int c = blockIdx.x;  // 0..1023: (bh, qi)
  int bh = c & 31, qi = c >> 5;
  int b = bh >> 4, h = bh & 15;
  int qraw = (qi - bh) & 31;
  size_t id0 = (size_t)bh + ((size_t)qraw << 6);
  size_t id1 = id0 + 32;
  int t = threadIdx.x;
  int r = t >> 2, cq = (t & 3) << 4;
  float m1 = ml_part[id0 * 128 + r * 2], l1 = ml_part[id0 * 128 + r * 2 + 1];
  float m2 = ml_part[id1 * 128 + r * 2], l2 = ml_part[id1 * 128 + r * 2 + 1];
  float mm = fmaxf(m1, m2);
  float w1 = __expf(m1 - mm), w2 = __expf(m2 - mm);
  float inv = 1.0f / (l1 * w1 + l2 * w2);
  const float* p1 = o_part + id0 * 4096 + r * 64 + cq;
  const float* p2 = o_part + id1 * 4096 + r * 64 + cq;
  bf16* yp = y + ((size_t)(b * 2048 + qi * 64 + r)) * 1024 + h * 64 + cq;
#pragma unroll
  for (int u = 0; u < 4; ++u) {
    float4 a = *(const float4*)(p1 + u * 4);
    float4 bq = *(const float4*)(p2 + u * 4);
    bf16x4 ov;
    ov[0] = (bf16)((a.x * w1 + bq.x * w2) * inv);
    ov[1] = (bf16)((a.y * w1 + bq.y * w2) * inv);
    ov[2] = (bf16)((a.z * w1 + bq.z * w2) * inv);
    ov[3] = (bf16)((a.w * w1 + bq.w * w2) * inv);
    *(bf16x4*)(yp + u * 4) = ov;
  }
}

// ---------------- launch ----------------
extern "C" void kernel_launch(void* const* d_in, const int* in_sizes, int n_in,
                              void* d_out, int out_size, void* d_ws, size_t ws_size,
                              hipStream_t stream) {
  const float* x = (const float*)d_in[0];
  const float* ln1_g = (const float*)d_in[1];
  const float* ln1_b = (const float*)d_in[2];
  const float* attn_w = (const float*)d_in[3];
  const float* attn_b = (const float*)d_in[4];
  const float* proj_w = (const float*)d_in[5];
  const float* proj_b = (const float*)d_in[6];
  const float* ln2_g = (const float*)d_in[7];
  const float* ln2_b = (const float*)d_in[8];
  const float* mlp_w1 = (const float*)d_in[9];
  const float* mlp_b1 = (const float*)d_in[10];
  const float* mlp_w2 = (const float*)d_in[11];
  const float* mlp_b2 = (const float*)d_in[12];
  const float* w_att = (const float*)d_in[13];
  const float* w_mlp = (const float*)d_in[14];
  float* out = (float*)d_out;

  unsigned char* base = nullptr;
  if (ws_size >= TOTAL_BYTES) {
    base = (unsigned char*)d_ws;
  } else {
    hipGetSymbolAddress((void**)&base, HIP_SYMBOL(g_buf));
  }
  bf16* bb = (bf16*)base;
  bf16* wt_attn = bb + E_WT_ATTN;
  bf16* wt_proj = bb + E_WT_PROJ;
  bf16* wt_mlp1 = bb + E_WT_MLP1;
  bf16* wt_mlp2 = bb + E_WT_MLP2;
  bf16* ln1o = bb + E_LN1;
  bf16* qkv = bb + E_QKV;
  bf16* qb = bb + E_Q;
  bf16* kb = bb + E_K;
  bf16* vTb = bb + E_VT;
  bf16* yb = bb + E_Y;
  bf16* ln2o = bb + E_LN2;
  bf16* hb = bb + E_H;
  float* x2 = (float*)(base + BYTE_X2);
  float* o_part = (float*)(base + BYTE_OPART);
  float* ml_part = (float*)(base + BYTE_ML);
  float* gpart = (float*)(base + BYTE_GPART);

  dim3 tb(32, 8);
  transpose_cast<<<dim3(3072 / 32, 1024 / 32), tb, 0, stream>>>(attn_w, wt_attn, 1024, 3072);
  transpose_cast<<<dim3(1024 / 32, 1024 / 32), tb, 0, stream>>>(proj_w, wt_proj, 1024, 1024);
  transpose_cast<<<dim3(4096 / 32, 1024 / 32), tb, 0, stream>>>(mlp_w1, wt_mlp1, 1024, 4096);
  transpose_cast<<<dim3(1024 / 32, 4096 / 32), tb, 0, stream>>>(mlp_w2, wt_mlp2, 4096, 1024);

  ln_bf16<<<4096, 256, 0, stream>>>(x, ln1_g, ln1_b, ln1o);

  gemm_bt<0><<<dim3(24, 32, 1), 256, 0, stream>>>(ln1o, wt_attn, attn_b, qkv, nullptr,
                                                  4096, 3072, 1024, 1024);

  split_qk<<<2048, 256, 0, stream>>>(qkv, qb, kb);
  split_v_t<<<dim3(64, 32), 256, 0, stream>>>(qkv, vTb);

  attn_fwd<<<2048, 256, 0, stream>>>(qb, kb, vTb, o_part, ml_part);
  attn_combine<<<1024, 256, 0, stream>>>(o_part, ml_part, yb);

  gemm_bt<3><<<dim3(8, 32, 2), 256, 0, stream>>>(yb, wt_proj, nullptr, nullptr, gpart,
                                                 4096, 1024, 1024, 512);
  reduce_add<2><<<4096, 256, 0, stream>>>(gpart, proj_b, x, w_att, x2, 4194304, 1024);

  ln_bf16<<<4096, 256, 0, stream>>>(x2, ln2_g, ln2_b, ln2o);

  gemm_bt<1><<<dim3(32, 32, 1), 256, 0, stream>>>(ln2o, wt_mlp1, mlp_b1, hb, nullptr,
                                                  4096, 4096, 1024, 1024);

  gemm_bt<3><<<dim3(8, 32, 4), 256, 0, stream>>>(hb, wt_mlp2, nullptr, nullptr, gpart,
                                                 4096, 1024, 4096, 1024);
  reduce_add<4><<<4096, 256, 0, stream>>>(gpart, mlp_b2, x2, w_mlp, out, 4194304, 1024);
}

// Round 4
// 448.618 us; speedup vs baseline: 1.3759x; 1.2312x over previous
//
#include <hip/hip_runtime.h>
#include <math.h>

typedef __bf16 bf16;
typedef bf16 bf16x8 __attribute__((ext_vector_type(8)));
typedef bf16 bf16x4 __attribute__((ext_vector_type(4)));
typedef float f32x4 __attribute__((ext_vector_type(4)));

#define MFMA(a, b, c) __builtin_amdgcn_mfma_f32_16x16x32_bf16((a), (b), (c), 0, 0, 0)

#define GLOAD_LDS16(gp, lp)                                                        \
  __builtin_amdgcn_global_load_lds((const __attribute__((address_space(1))) void*)(gp), \
                                   (__attribute__((address_space(3))) void*)(lp), 16, 0, 0)

// ---------------- workspace layout ----------------
// bf16 element offsets
static const size_t E_WT_ATTN = 0;          // [3072][1024]
static const size_t E_WT_PROJ = 3145728;    // [1024][1024]
static const size_t E_WT_MLP1 = 4194304;    // [4096][1024]
static const size_t E_WT_MLP2 = 8388608;    // [1024][4096]
static const size_t E_LN1     = 12582912;   // [4096][1024]
static const size_t E_QKV     = 16777216;   // [4096][3072]
static const size_t E_VT      = 37748736;   // [B,H,64,T]
static const size_t E_Y       = 41943040;   // [4096][1024]
static const size_t E_LN2     = 46137344;   // [4096][1024]
static const size_t E_H       = 50331648;   // [4096][4096]
// byte offsets
static const size_t BYTE_X2    = 134217728; // float [4096][1024]
static const size_t BYTE_OPART = 150994944; // float [2048][64][64] attn partials
static const size_t BYTE_ML    = 184549376; // float [2048][64][2]
static const size_t BYTE_GPART = 185597952; // float [4][4096][1024] gemm split-K partials
static const size_t TOTAL_BYTES = 252706816;

__device__ __align__(4096) unsigned char g_buf[TOTAL_BYTES];

// ---------------- transpose + cast: in f32 [K][N] -> out bf16 [N][K] ----------------
__global__ __launch_bounds__(256) void transpose_cast(const float* __restrict__ in,
                                                      bf16* __restrict__ out, int K, int N) {
  __shared__ float tile[32][33];
  int bx = blockIdx.x, by = blockIdx.y;
  int tx = threadIdx.x, ty = threadIdx.y;
#pragma unroll
  for (int i = ty; i < 32; i += 8)
    tile[i][tx] = in[(size_t)(by * 32 + i) * N + bx * 32 + tx];
  __syncthreads();
#pragma unroll
  for (int i = ty; i < 32; i += 8)
    out[(size_t)(bx * 32 + i) * K + by * 32 + tx] = (bf16)tile[tx][i];
}

// ---------------- LayerNorm f32 row(1024) -> bf16 ----------------
__global__ __launch_bounds__(256) void ln_bf16(const float* __restrict__ x,
                                               const float* __restrict__ g,
                                               const float* __restrict__ b,
                                               bf16* __restrict__ out) {
  int row = blockIdx.x, tid = threadIdx.x;
  const float* xr = x + ((size_t)row << 10);
  float4 v = *(const float4*)(xr + tid * 4);
  float s = v.x + v.y + v.z + v.w;
  float ss = v.x * v.x + v.y * v.y + v.z * v.z + v.w * v.w;
#pragma unroll
  for (int off = 32; off >= 1; off >>= 1) {
    s += __shfl_down(s, off);
    ss += __shfl_down(ss, off);
  }
  __shared__ float sh[8];
  int wid = tid >> 6;
  if ((tid & 63) == 0) { sh[wid] = s; sh[wid + 4] = ss; }
  __syncthreads();
  float ts = sh[0] + sh[1] + sh[2] + sh[3];
  float tss = sh[4] + sh[5] + sh[6] + sh[7];
  float mean = ts * (1.0f / 1024.0f);
  float var = tss * (1.0f / 1024.0f) - mean * mean;
  float inv = rsqrtf(var + 1e-5f);
  float4 gg = *(const float4*)(g + tid * 4);
  float4 bb = *(const float4*)(b + tid * 4);
  bf16x4 o;
  o[0] = (bf16)((v.x - mean) * inv * gg.x + bb.x);
  o[1] = (bf16)((v.y - mean) * inv * gg.y + bb.y);
  o[2] = (bf16)((v.z - mean) * inv * gg.z + bb.z);
  o[3] = (bf16)((v.w - mean) * inv * gg.w + bb.w);
  *(bf16x4*)(out + ((size_t)row << 10) + tid * 4) = o;
}

// ---------------- GEMM: C[M][N] = A[M][K](bf16) @ Bt[N][K]^T ----------------
// EPI 0: outb = bf16(acc+bias); EPI 1: outb = bf16(gelu(acc+bias));
// EPI 3: outf[z*M*N + idx] = acc (split-K partial, no bias)
template <int EPI>
__global__ __launch_bounds__(256) void gemm_bt(const bf16* __restrict__ A,
                                               const bf16* __restrict__ Bt,
                                               const float* __restrict__ bias,
                                               bf16* __restrict__ outb,
                                               float* __restrict__ outf,
                                               int M, int N, int K, int Kseg) {
  __shared__ __align__(16) bf16 As[128 * 32];
  __shared__ __align__(16) bf16 Bs[128 * 32];
  int bx = blockIdx.x, by = blockIdx.y;
  int tid = threadIdx.x;
  int lane = tid & 63, wid = tid >> 6;
  int wr = wid >> 1, wc = wid & 1;
  int g = lane >> 4, lr = lane & 15;
  f32x4 acc[4][4];
#pragma unroll
  for (int m = 0; m < 4; ++m)
#pragma unroll
    for (int n = 0; n < 4; ++n) acc[m][n] = (f32x4){0.f, 0.f, 0.f, 0.f};
  const bf16* Ab = A + (size_t)by * 128 * K;
  const bf16* Bb = Bt + (size_t)bx * 128 * K;
  int srow = tid >> 2;
  int sk8 = (tid & 3) * 8;
  const bf16* Ap0 = Ab + (size_t)srow * K + sk8;
  const bf16* Ap1 = Ab + (size_t)(srow + 64) * K + sk8;
  const bf16* Bp0 = Bb + (size_t)srow * K + sk8;
  const bf16* Bp1 = Bb + (size_t)(srow + 64) * K + sk8;
  bf16* lA0 = As + tid * 8;
  bf16* lA1 = As + 2048 + tid * 8;
  bf16* lB0 = Bs + tid * 8;
  bf16* lB1 = Bs + 2048 + tid * 8;
  int kbeg = blockIdx.z * Kseg;
  int kend = kbeg + Kseg;
  for (int k0 = kbeg; k0 < kend; k0 += 32) {
    GLOAD_LDS16(Ap0 + k0, lA0);
    GLOAD_LDS16(Ap1 + k0, lA1);
    GLOAD_LDS16(Bp0 + k0, lB0);
    GLOAD_LDS16(Bp1 + k0, lB1);
    __syncthreads();
    bf16x8 af[4], bfv[4];
#pragma unroll
    for (int m = 0; m < 4; ++m) af[m] = *(const bf16x8*)(As + (wr * 64 + m * 16 + lr) * 32 + g * 8);
#pragma unroll
    for (int n = 0; n < 4; ++n) bfv[n] = *(const bf16x8*)(Bs + (wc * 64 + n * 16 + lr) * 32 + g * 8);
#pragma unroll
    for (int m = 0; m < 4; ++m)
#pragma unroll
      for (int n = 0; n < 4; ++n) acc[m][n] = MFMA(af[m], bfv[n], acc[m][n]);
    __syncthreads();
  }
  if (EPI == 3) {
    float* po = outf + (size_t)blockIdx.z * M * N;
#pragma unroll
    for (int m = 0; m < 4; ++m) {
#pragma unroll
      for (int n = 0; n < 4; ++n) {
        int rg0 = by * 128 + wr * 64 + m * 16 + g * 4;
        int cg = bx * 128 + wc * 64 + n * 16 + lr;
#pragma unroll
        for (int j = 0; j < 4; ++j) po[(size_t)(rg0 + j) * N + cg] = acc[m][n][j];
      }
    }
  } else {
#pragma unroll
    for (int m = 0; m < 4; ++m) {
#pragma unroll
      for (int n = 0; n < 4; ++n) {
        int rg0 = by * 128 + wr * 64 + m * 16 + g * 4;
        int cg = bx * 128 + wc * 64 + n * 16 + lr;
        float bv = bias[cg];
#pragma unroll
        for (int j = 0; j < 4; ++j) {
          float v = acc[m][n][j] + bv;
          size_t idx = (size_t)(rg0 + j) * N + cg;
          if (EPI == 0)
            outb[idx] = (bf16)v;
          else
            outb[idx] = (bf16)(0.5f * v * (1.0f + erff(v * 0.70710678118f)));
        }
      }
    }
  }
}

// ---------------- split-K reduce: out = res*w + sum(parts) + bias ----------------
template <int SK>
__global__ __launch_bounds__(256) void reduce_add(const float* __restrict__ part,
                                                  const float* __restrict__ bias,
                                                  const float* __restrict__ res,
                                                  const float* __restrict__ wsc,
                                                  float* __restrict__ out, int MN, int N) {
  size_t i = ((size_t)blockIdx.x * 256 + threadIdx.x) * 4;
  float4 a = *(const float4*)(part + i);
#pragma unroll
  for (int s = 1; s < SK; ++s) {
    float4 b = *(const float4*)(part + (size_t)s * MN + i);
    a.x += b.x; a.y += b.y; a.z += b.z; a.w += b.w;
  }
  int col = (int)(i & (size_t)(N - 1));
  float4 bv = *(const float4*)(bias + col);
  float4 rv = *(const float4*)(res + i);
  float w = wsc[0];
  float4 o;
  o.x = rv.x * w + a.x + bv.x;
  o.y = rv.y * w + a.y + bv.y;
  o.z = rv.z * w + a.z + bv.z;
  o.w = rv.w * w + a.w + bv.w;
  *(float4*)(out + i) = o;
}

// ---------------- fused proj split-K reduce + residual + LayerNorm2 ----------------
// one block per row (1024 cols): x2 = res*w + part0 + part1 + bias; ln2o = LN(x2)
__global__ __launch_bounds__(256) void reduce_ln(const float* __restrict__ part,
                                                 const float* __restrict__ bias,
                                                 const float* __restrict__ res,
                                                 const float* __restrict__ wsc,
                                                 const float* __restrict__ lng,
                                                 const float* __restrict__ lnb,
                                                 float* __restrict__ x2out,
                                                 bf16* __restrict__ lnout) {
  int row = blockIdx.x, tid = threadIdx.x;
  size_t i = ((size_t)row << 10) + tid * 4;
  float4 a = *(const float4*)(part + i);
  float4 b2 = *(const float4*)(part + 4194304 + i);
  float4 rv = *(const float4*)(res + i);
  float4 bv = *(const float4*)(bias + tid * 4);
  float w = wsc[0];
  float4 o;
  o.x = rv.x * w + a.x + b2.x + bv.x;
  o.y = rv.y * w + a.y + b2.y + bv.y;
  o.z = rv.z * w + a.z + b2.z + bv.z;
  o.w = rv.w * w + a.w + b2.w + bv.w;
  *(float4*)(x2out + i) = o;
  float s = o.x + o.y + o.z + o.w;
  float ss = o.x * o.x + o.y * o.y + o.z * o.z + o.w * o.w;
#pragma unroll
  for (int off = 32; off >= 1; off >>= 1) {
    s += __shfl_down(s, off);
    ss += __shfl_down(ss, off);
  }
  __shared__ float sh[8];
  int wid = tid >> 6;
  if ((tid & 63) == 0) { sh[wid] = s; sh[wid + 4] = ss; }
  __syncthreads();
  float ts = sh[0] + sh[1] + sh[2] + sh[3];
  float tss = sh[4] + sh[5] + sh[6] + sh[7];
  float mean = ts * (1.0f / 1024.0f);
  float var = tss * (1.0f / 1024.0f) - mean * mean;
  float inv = rsqrtf(var + 1e-5f);
  float4 gg = *(const float4*)(lng + tid * 4);
  float4 bb = *(const float4*)(lnb + tid * 4);
  bf16x4 ov;
  ov[0] = (bf16)((o.x - mean) * inv * gg.x + bb.x);
  ov[1] = (bf16)((o.y - mean) * inv * gg.y + bb.y);
  ov[2] = (bf16)((o.z - mean) * inv * gg.z + bb.z);
  ov[3] = (bf16)((o.w - mean) * inv * gg.w + bb.w);
  *(bf16x4*)(lnout + ((size_t)row << 10) + tid * 4) = ov;
}

// ---------------- V transpose from qkv: vT[bh][d][t] ----------------
__global__ __launch_bounds__(256) void split_v_t(const bf16* __restrict__ qkv,
                                                 bf16* __restrict__ vT) {
  int t0 = blockIdx.x * 32;
  int bh = blockIdx.y;
  int b = bh >> 4, h = bh & 15;
  __shared__ bf16 tile[32][72];
  int tid = threadIdx.x;
  int d = tid & 63, tl0 = tid >> 6;
#pragma unroll
  for (int p = 0; p < 8; ++p) {
    int tl = p * 4 + tl0;
    tile[tl][d] = qkv[((size_t)(b * 2048 + t0 + tl)) * 3072 + 2048 + h * 64 + d];
  }
  __syncthreads();
  int tl = tid & 31, dq = tid >> 5;
#pragma unroll
  for (int p = 0; p < 8; ++p) {
    int dd = p * 8 + dq;
    vT[((size_t)(bh * 64 + dd)) * 2048 + t0 + tl] = tile[tl][dd];
  }
}

// ---------------- flash attention fwd (LDS-staged K/V, double-buffered, split-K=2) ----------------
// Q,K read from qkv directly; V from vT [bh][64][2048].
// o_part [2048][64][64] f32, ml_part [2048][64][2] (m in log2-domain)
__global__ __launch_bounds__(256) void attn_fwd(const bf16* __restrict__ qkv,
                                                const bf16* __restrict__ vT,
                                                float* __restrict__ o_part,
                                                float* __restrict__ ml_part) {
  __shared__ __align__(16) bf16 Ks[2][4096];
  __shared__ __align__(16) bf16 Vs[2][4096];
  __shared__ bf16 P[4][16][72];
  int id = blockIdx.x;            // 0..2047
  int bh = id & 31;
  int seg = (id >> 5) & 1;
  int qi = ((id >> 6) + bh) & 31; // stagger causal depth
  int tid = threadIdx.x, wid = tid >> 6, lane = tid & 63;
  int g = lane >> 4, lr = lane & 15;
  int b = bh >> 4, h = bh & 15;
  int nk = qi + 1;
  int n0 = (nk + 1) >> 1;
  int kt0 = seg ? n0 : 0;
  int kt1 = seg ? nk : n0;
  int qrow = qi * 64 + wid * 16 + lr;
  // Q fragment straight from qkv
  const bf16* Qr = qkv + ((size_t)(b * 2048 + qrow)) * 3072 + h * 64;
  bf16x8 qf[2];
  qf[0] = *(const bf16x8*)(Qr + g * 8);
  qf[1] = *(const bf16x8*)(Qr + 32 + g * 8);
  // staging: 512 chunks of 16B per 8KB tile; thread handles chunks tid and tid+256.
  // XOR-swizzle: LDS chunk c holds global col-chunk (c&7)^(row&7) of row c>>3.
  int r0 = tid >> 3, cs0 = ((tid & 7) ^ (r0 & 7)) << 3;
  int c1i = tid + 256;
  int r1 = c1i >> 3, cs1 = ((c1i & 7) ^ (r1 & 7)) << 3;
  const bf16* sK0 = qkv + ((size_t)(b * 2048 + r0)) * 3072 + 1024 + h * 64 + cs0;
  const bf16* sK1 = qkv + ((size_t)(b * 2048 + r1)) * 3072 + 1024 + h * 64 + cs1;
  const bf16* sV0 = vT + (size_t)bh * 131072 + (size_t)r0 * 2048 + cs0;
  const bf16* sV1 = vT + (size_t)bh * 131072 + (size_t)r1 * 2048 + cs1;
  bf16* dK0 = &Ks[0][0] + tid * 8;
  bf16* dK1 = &Ks[0][0] + 2048 + tid * 8;
  bf16* dV0 = &Vs[0][0] + tid * 8;
  bf16* dV1 = &Vs[0][0] + 2048 + tid * 8;
#define ATTN_STAGE(bufsel, ktv)                          \
  {                                                      \
    size_t kadv = (size_t)(ktv) * (64 * 3072);           \
    size_t vadv = (size_t)(ktv) * 64;                    \
    int bo = (bufsel) * 4096;                            \
    GLOAD_LDS16(sK0 + kadv, dK0 + bo);                   \
    GLOAD_LDS16(sK1 + kadv, dK1 + bo);                   \
    GLOAD_LDS16(sV0 + vadv, dV0 + bo);                   \
    GLOAD_LDS16(sV1 + vadv, dV1 + bo);                   \
  }
  f32x4 o[4];
#pragma unroll
  for (int n = 0; n < 4; ++n) o[n] = (f32x4){0.f, 0.f, 0.f, 0.f};
  float m = -3e38f, l = 0.f;
  if (kt0 < kt1) ATTN_STAGE(0, kt0);
  __syncthreads();
  const float beta = 0.18033688f;  // 0.125 * log2(e): softmax in exp2 domain
  int sw = lr & 7;
  int sb = (lane & 48) | (g << 2); // source-lane base for al broadcast
  for (int kt = kt0; kt < kt1; ++kt) {
    int cur = (kt - kt0) & 1;
    if (kt + 1 < kt1) ATTN_STAGE(cur ^ 1, kt + 1);
    const bf16* Kb = &Ks[cur][0];
    const bf16* Vb = &Vs[cur][0];
    f32x4 s[4];
#pragma unroll
    for (int n = 0; n < 4; ++n) s[n] = (f32x4){0.f, 0.f, 0.f, 0.f};
#pragma unroll
    for (int kk = 0; kk < 2; ++kk) {
#pragma unroll
      for (int n = 0; n < 4; ++n) {
        bf16x8 kf = *(const bf16x8*)(Kb + ((n * 16 + lr) << 6) + ((((kk << 2) + g) ^ sw) << 3));
        s[n] = MFMA(kf, qf[kk], s[n]);  // S^T: lane holds q-row lr, k-cols n*16+g*4+j
      }
    }
    int kc0 = kt * 64 + g * 4;
#pragma unroll
    for (int n = 0; n < 4; ++n)
#pragma unroll
      for (int j = 0; j < 4; ++j) {
        float sv = s[n][j] * beta;
        s[n][j] = ((kc0 + n * 16 + j) <= qrow) ? sv : -3e38f;
      }
    float mx = s[0][0];
#pragma unroll
    for (int n = 0; n < 4; ++n)
#pragma unroll
      for (int j = 0; j < 4; ++j) mx = fmaxf(mx, s[n][j]);
    mx = fmaxf(mx, __shfl_xor(mx, 16));
    mx = fmaxf(mx, __shfl_xor(mx, 32));
    float mn = fmaxf(m, mx);
    float al = exp2f(m - mn);
    m = mn;
    float rs = 0.f;
    bf16x4 pw[4];
#pragma unroll
    for (int n = 0; n < 4; ++n)
#pragma unroll
      for (int j = 0; j < 4; ++j) {
        float p = exp2f(s[n][j] - mn);
        rs += p;
        pw[n][j] = (bf16)p;
      }
    rs += __shfl_xor(rs, 16);
    rs += __shfl_xor(rs, 32);
    l = l * al + rs;
    float alj[4];
#pragma unroll
    for (int j = 0; j < 4; ++j) alj[j] = __shfl(al, sb + j);
#pragma unroll
    for (int n = 0; n < 4; ++n)
#pragma unroll
      for (int j = 0; j < 4; ++j) o[n][j] *= alj[j];
#pragma unroll
    for (int n = 0; n < 4; ++n) *(bf16x4*)&P[wid][lr][n * 16 + g * 4] = pw[n];
#pragma unroll
    for (int kk = 0; kk < 2; ++kk) {
      bf16x8 pf = *(const bf16x8*)&P[wid][lr][kk * 32 + g * 8];
#pragma unroll
      for (int n = 0; n < 4; ++n) {
        bf16x8 vf = *(const bf16x8*)(Vb + ((n * 16 + lr) << 6) + ((((kk << 2) + g) ^ sw) << 3));
        o[n] = MFMA(pf, vf, o[n]);
      }
    }
    __syncthreads();
  }
  float* ob = o_part + (size_t)id * 4096;
#pragma unroll
  for (int n = 0; n < 4; ++n)
#pragma unroll
    for (int j = 0; j < 4; ++j)
      ob[(size_t)(wid * 16 + g * 4 + j) * 64 + n * 16 + lr] = o[n][j];
  if (lane < 16) {
    ml_part[(size_t)id * 128 + (wid * 16 + lane) * 2] = m;
    ml_part[(size_t)id * 128 + (wid * 16 + lane) * 2 + 1] = l;
  }
#undef ATTN_STAGE
}

// ---------------- attention combine: merge 2 segments, normalize, write y ----------------
__global__ __launch_bounds__(256) void attn_combine(const float* __restrict__ o_part,
                                                    const float* __restrict__ ml_part,
                                                    bf16* __restrict__ y) {
  int c = blockIdx.x;  // 0..1023: (bh, qi)
  int bh = c & 31, qi = c >> 5;
  int b = bh >> 4, h = bh & 15;
  int qraw = (qi - bh) & 31;
  size_t id0 = (size_t)bh + ((size_t)qraw << 6);
  size_t id1 = id0 + 32;
  int t = threadIdx.x;
  int r = t >> 2, cq = (t & 3) << 4;
  float m1 = ml_part[id0 * 128 + r * 2], l1 = ml_part[id0 * 128 + r * 2 + 1];
  float m2 = ml_part[id1 * 128 + r * 2], l2 = ml_part[id1 * 128 + r * 2 + 1];
  float mm = fmaxf(m1, m2);
  float w1 = exp2f(m1 - mm), w2 = exp2f(m2 - mm);
  float inv = 1.0f / (l1 * w1 + l2 * w2);
  const float* p1 = o_part + id0 * 4096 + r * 64 + cq;
  const float* p2 = o_part + id1 * 4096 + r * 64 + cq;
  bf16* yp = y + ((size_t)(b * 2048 + qi * 64 + r)) * 1024 + h * 64 + cq;
#pragma unroll
  for (int u = 0; u < 4; ++u) {
    float4 a = *(const float4*)(p1 + u * 4);
    float4 bq = *(const float4*)(p2 + u * 4);
    bf16x4 ov;
    ov[0] = (bf16)((a.x * w1 + bq.x * w2) * inv);
    ov[1] = (bf16)((a.y * w1 + bq.y * w2) * inv);
    ov[2] = (bf16)((a.z * w1 + bq.z * w2) * inv);
    ov[3] = (bf16)((a.w * w1 + bq.w * w2) * inv);
    *(bf16x4*)(yp + u * 4) = ov;
  }
}

// ---------------- launch ----------------
extern "C" void kernel_launch(void* const* d_in, const int* in_sizes, int n_in,
                              void* d_out, int out_size, void* d_ws, size_t ws_size,
                              hipStream_t stream) {
  const float* x = (const float*)d_in[0];
  const float* ln1_g = (const float*)d_in[1];
  const float* ln1_b = (const float*)d_in[2];
  const float* attn_w = (const float*)d_in[3];
  const float* attn_b = (const float*)d_in[4];
  const float* proj_w = (const float*)d_in[5];
  const float* proj_b = (const float*)d_in[6];
  const float* ln2_g = (const float*)d_in[7];
  const float* ln2_b = (const float*)d_in[8];
  const float* mlp_w1 = (const float*)d_in[9];
  const float* mlp_b1 = (const float*)d_in[10];
  const float* mlp_w2 = (const float*)d_in[11];
  const float* mlp_b2 = (const float*)d_in[12];
  const float* w_att = (const float*)d_in[13];
  const float* w_mlp = (const float*)d_in[14];
  float* out = (float*)d_out;

  unsigned char* base = nullptr;
  if (ws_size >= TOTAL_BYTES) {
    base = (unsigned char*)d_ws;
  } else {
    hipGetSymbolAddress((void**)&base, HIP_SYMBOL(g_buf));
  }
  bf16* bb = (bf16*)base;
  bf16* wt_attn = bb + E_WT_ATTN;
  bf16* wt_proj = bb + E_WT_PROJ;
  bf16* wt_mlp1 = bb + E_WT_MLP1;
  bf16* wt_mlp2 = bb + E_WT_MLP2;
  bf16* ln1o = bb + E_LN1;
  bf16* qkv = bb + E_QKV;
  bf16* vTb = bb + E_VT;
  bf16* yb = bb + E_Y;
  bf16* ln2o = bb + E_LN2;
  bf16* hb = bb + E_H;
  float* x2 = (float*)(base + BYTE_X2);
  float* o_part = (float*)(base + BYTE_OPART);
  float* ml_part = (float*)(base + BYTE_ML);
  float* gpart = (float*)(base + BYTE_GPART);

  dim3 tb(32, 8);
  transpose_cast<<<dim3(3072 / 32, 1024 / 32), tb, 0, stream>>>(attn_w, wt_attn, 1024, 3072);
  transpose_cast<<<dim3(1024 / 32, 1024 / 32), tb, 0, stream>>>(proj_w, wt_proj, 1024, 1024);
  transpose_cast<<<dim3(4096 / 32, 1024 / 32), tb, 0, stream>>>(mlp_w1, wt_mlp1, 1024, 4096);
  transpose_cast<<<dim3(1024 / 32, 4096 / 32), tb, 0, stream>>>(mlp_w2, wt_mlp2, 4096, 1024);

  ln_bf16<<<4096, 256, 0, stream>>>(x, ln1_g, ln1_b, ln1o);

  gemm_bt<0><<<dim3(24, 32, 1), 256, 0, stream>>>(ln1o, wt_attn, attn_b, qkv, nullptr,
                                                  4096, 3072, 1024, 1024);

  split_v_t<<<dim3(64, 32), 256, 0, stream>>>(qkv, vTb);

  attn_fwd<<<2048, 256, 0, stream>>>(qkv, vTb, o_part, ml_part);
  attn_combine<<<1024, 256, 0, stream>>>(o_part, ml_part, yb);

  gemm_bt<3><<<dim3(8, 32, 2), 256, 0, stream>>>(yb, wt_proj, nullptr, nullptr, gpart,
                                                 4096, 1024, 1024, 512);
  reduce_ln<<<4096, 256, 0, stream>>>(gpart, proj_b, x, w_att, ln2_g, ln2_b, x2, ln2o);

  gemm_bt<1><<<dim3(32, 32, 1), 256, 0, stream>>>(ln2o, wt_mlp1, mlp_b1, hb, nullptr,
                                                  4096, 4096, 1024, 1024);

  gemm_bt<3><<<dim3(8, 32, 4), 256, 0, stream>>>(hb, wt_mlp2, nullptr, nullptr, gpart,
                                                 4096, 1024, 4096, 1024);
  reduce_add<4><<<4096, 256, 0, stream>>>(gpart, mlp_b2, x2, w_mlp, out, 4194304, 1024);
}

// Round 5
// 403.987 us; speedup vs baseline: 1.5279x; 1.1105x over previous
//
#include <hip/hip_runtime.h>
#include <math.h>

typedef __bf16 bf16;
typedef bf16 bf16x8 __attribute__((ext_vector_type(8)));
typedef bf16 bf16x4 __attribute__((ext_vector_type(4)));
typedef float f32x4 __attribute__((ext_vector_type(4)));

#define MFMA(a, b, c) __builtin_amdgcn_mfma_f32_16x16x32_bf16((a), (b), (c), 0, 0, 0)

#define GLOAD_LDS16(gp, lp)                                                        \
  __builtin_amdgcn_global_load_lds((const __attribute__((address_space(1))) void*)(gp), \
                                   (__attribute__((address_space(3))) void*)(lp), 16, 0, 0)

// ---------------- workspace layout ----------------
// bf16 element offsets
static const size_t E_WT_ATTN = 0;          // [3072][1024]
static const size_t E_WT_PROJ = 3145728;    // [1024][1024]
static const size_t E_WT_MLP1 = 4194304;    // [4096][1024]
static const size_t E_WT_MLP2 = 8388608;    // [1024][4096]
static const size_t E_LN1     = 12582912;   // [4096][1024]
static const size_t E_QKV     = 16777216;   // [4096][3072]
static const size_t E_VT      = 37748736;   // [B,H,64,T]
static const size_t E_Y       = 41943040;   // [4096][1024]
static const size_t E_LN2     = 46137344;   // [4096][1024]
static const size_t E_H       = 50331648;   // [4096][4096]
// byte offsets
static const size_t BYTE_X2    = 134217728; // float [4096][1024]
static const size_t BYTE_OPART = 150994944; // float [2048][64][64] attn partials
static const size_t BYTE_ML    = 184549376; // float [2048][64][2]
static const size_t BYTE_GPART = 185597952; // float [4][4096][1024] gemm split-K partials
static const size_t TOTAL_BYTES = 252706816;

__device__ __align__(4096) unsigned char g_buf[TOTAL_BYTES];

// ---------------- transpose + cast: in f32 [K][N] -> out bf16 [N][K] ----------------
__global__ __launch_bounds__(256) void transpose_cast(const float* __restrict__ in,
                                                      bf16* __restrict__ out, int K, int N) {
  __shared__ float tile[32][33];
  int bx = blockIdx.x, by = blockIdx.y;
  int tx = threadIdx.x, ty = threadIdx.y;
#pragma unroll
  for (int i = ty; i < 32; i += 8)
    tile[i][tx] = in[(size_t)(by * 32 + i) * N + bx * 32 + tx];
  __syncthreads();
#pragma unroll
  for (int i = ty; i < 32; i += 8)
    out[(size_t)(bx * 32 + i) * K + by * 32 + tx] = (bf16)tile[tx][i];
}

// ---------------- LayerNorm f32 row(1024) -> bf16 ----------------
__global__ __launch_bounds__(256) void ln_bf16(const float* __restrict__ x,
                                               const float* __restrict__ g,
                                               const float* __restrict__ b,
                                               bf16* __restrict__ out) {
  int row = blockIdx.x, tid = threadIdx.x;
  const float* xr = x + ((size_t)row << 10);
  float4 v = *(const float4*)(xr + tid * 4);
  float s = v.x + v.y + v.z + v.w;
  float ss = v.x * v.x + v.y * v.y + v.z * v.z + v.w * v.w;
#pragma unroll
  for (int off = 32; off >= 1; off >>= 1) {
    s += __shfl_down(s, off);
    ss += __shfl_down(ss, off);
  }
  __shared__ float sh[8];
  int wid = tid >> 6;
  if ((tid & 63) == 0) { sh[wid] = s; sh[wid + 4] = ss; }
  __syncthreads();
  float ts = sh[0] + sh[1] + sh[2] + sh[3];
  float tss = sh[4] + sh[5] + sh[6] + sh[7];
  float mean = ts * (1.0f / 1024.0f);
  float var = tss * (1.0f / 1024.0f) - mean * mean;
  float inv = rsqrtf(var + 1e-5f);
  float4 gg = *(const float4*)(g + tid * 4);
  float4 bb = *(const float4*)(b + tid * 4);
  bf16x4 o;
  o[0] = (bf16)((v.x - mean) * inv * gg.x + bb.x);
  o[1] = (bf16)((v.y - mean) * inv * gg.y + bb.y);
  o[2] = (bf16)((v.z - mean) * inv * gg.z + bb.z);
  o[3] = (bf16)((v.w - mean) * inv * gg.w + bb.w);
  *(bf16x4*)(out + ((size_t)row << 10) + tid * 4) = o;
}

// ---------------- 256x256 GEMM, BK=64, 8 waves, dbuf LDS, swizzled ----------------
// C[M][N] = A[M][K] @ Bt[N][K]^T. EPI 0: bf16(acc+bias); 1: bf16(gelu(acc+bias));
// 3: outf[z*M*N+idx] = acc (split-K partial)
template <int EPI>
__global__ __launch_bounds__(512, 2) void gemm256(const bf16* __restrict__ A,
                                                  const bf16* __restrict__ Bt,
                                                  const float* __restrict__ bias,
                                                  bf16* __restrict__ outb,
                                                  float* __restrict__ outf,
                                                  int M, int N, int K, int Kseg) {
  __shared__ __align__(16) bf16 As[2][16384];  // [buf][256*64]
  __shared__ __align__(16) bf16 Bs[2][16384];
  int tid = threadIdx.x;
  // XCD-contiguous tile remap (nwg % 8 == 0 for all our grids)
  int nwg = gridDim.x * gridDim.y;
  int bid = blockIdx.y * gridDim.x + blockIdx.x;
  int id2 = ((nwg & 7) == 0) ? ((bid & 7) * (nwg >> 3) + (bid >> 3)) : bid;
  int bx = id2 % gridDim.x, by = id2 / gridDim.x;
  int lane = tid & 63, wid = tid >> 6;
  int wr = wid >> 2, wc = wid & 3;  // 2 x 4 waves
  int g = lane >> 4, lr = lane & 15;
  f32x4 acc[8][4];
#pragma unroll
  for (int m = 0; m < 8; ++m)
#pragma unroll
    for (int n = 0; n < 4; ++n) acc[m][n] = (f32x4){0.f, 0.f, 0.f, 0.f};
  const bf16* Ab = A + (size_t)by * 256 * K;
  const bf16* Bb = Bt + (size_t)bx * 256 * K;
  // staging: thread handles 16B chunks p = tid + 512*q (q=0..3) of the 2048-chunk tile.
  // LDS chunk (row, c) holds global col-chunk c^(row&7) (row&7 invariant across q since 64q%8==0)
  int rbase = tid >> 3;
  int srccol = (((tid & 7) ^ (rbase & 7)) << 3);
  const bf16* Asrc = Ab + (size_t)rbase * K + srccol;
  const bf16* Bsrc = Bb + (size_t)rbase * K + srccol;
#define G256_STAGE(buf, k0)                                                \
  {                                                                        \
    _Pragma("unroll") for (int q = 0; q < 4; ++q) {                        \
      GLOAD_LDS16(Asrc + (size_t)(q * 64) * K + (k0), &As[buf][tid * 8 + q * 4096]); \
      GLOAD_LDS16(Bsrc + (size_t)(q * 64) * K + (k0), &Bs[buf][tid * 8 + q * 4096]); \
    }                                                                      \
  }
  int kbeg = blockIdx.z * Kseg;
  int NT = Kseg >> 6;
  G256_STAGE(0, kbeg);
  __syncthreads();
  int c = 0;
  for (int t = 0; t < NT; ++t) {
    if (t + 1 < NT) G256_STAGE(c ^ 1, kbeg + (t + 1) * 64);
#pragma unroll
    for (int kk = 0; kk < 2; ++kk) {
      bf16x8 af[8], bfv[4];
#pragma unroll
      for (int m = 0; m < 8; ++m) {
        int row = wr * 128 + m * 16 + lr;
        af[m] = *(const bf16x8*)&As[c][row * 64 + ((((kk << 2) + g) ^ (row & 7)) << 3)];
      }
#pragma unroll
      for (int n = 0; n < 4; ++n) {
        int row = wc * 64 + n * 16 + lr;
        bfv[n] = *(const bf16x8*)&Bs[c][row * 64 + ((((kk << 2) + g) ^ (row & 7)) << 3)];
      }
#pragma unroll
      for (int m = 0; m < 8; ++m)
#pragma unroll
        for (int n = 0; n < 4; ++n) acc[m][n] = MFMA(af[m], bfv[n], acc[m][n]);
    }
    __syncthreads();
    c ^= 1;
  }
#undef G256_STAGE
  if (EPI == 3) {
    float* po = outf + (size_t)blockIdx.z * M * N;
#pragma unroll
    for (int m = 0; m < 8; ++m) {
#pragma unroll
      for (int n = 0; n < 4; ++n) {
        int rg0 = by * 256 + wr * 128 + m * 16 + g * 4;
        int cg = bx * 256 + wc * 64 + n * 16 + lr;
#pragma unroll
        for (int j = 0; j < 4; ++j) po[(size_t)(rg0 + j) * N + cg] = acc[m][n][j];
      }
    }
  } else {
#pragma unroll
    for (int m = 0; m < 8; ++m) {
#pragma unroll
      for (int n = 0; n < 4; ++n) {
        int rg0 = by * 256 + wr * 128 + m * 16 + g * 4;
        int cg = bx * 256 + wc * 64 + n * 16 + lr;
        float bv = bias[cg];
#pragma unroll
        for (int j = 0; j < 4; ++j) {
          float v = acc[m][n][j] + bv;
          size_t idx = (size_t)(rg0 + j) * N + cg;
          if (EPI == 0)
            outb[idx] = (bf16)v;
          else
            outb[idx] = (bf16)(0.5f * v * (1.0f + erff(v * 0.70710678118f)));
        }
      }
    }
  }
}

// ---------------- 128x128 GEMM (split-K partial only) ----------------
__global__ __launch_bounds__(256) void gemm_bt3(const bf16* __restrict__ A,
                                                const bf16* __restrict__ Bt,
                                                float* __restrict__ outf,
                                                int M, int N, int K, int Kseg) {
  __shared__ __align__(16) bf16 As[128 * 32];
  __shared__ __align__(16) bf16 Bs[128 * 32];
  int bx = blockIdx.x, by = blockIdx.y;
  int tid = threadIdx.x;
  int lane = tid & 63, wid = tid >> 6;
  int wr = wid >> 1, wc = wid & 1;
  int g = lane >> 4, lr = lane & 15;
  f32x4 acc[4][4];
#pragma unroll
  for (int m = 0; m < 4; ++m)
#pragma unroll
    for (int n = 0; n < 4; ++n) acc[m][n] = (f32x4){0.f, 0.f, 0.f, 0.f};
  const bf16* Ab = A + (size_t)by * 128 * K;
  const bf16* Bb = Bt + (size_t)bx * 128 * K;
  int srow = tid >> 2;
  int sk8 = (tid & 3) * 8;
  const bf16* Ap0 = Ab + (size_t)srow * K + sk8;
  const bf16* Ap1 = Ab + (size_t)(srow + 64) * K + sk8;
  const bf16* Bp0 = Bb + (size_t)srow * K + sk8;
  const bf16* Bp1 = Bb + (size_t)(srow + 64) * K + sk8;
  bf16* lA0 = As + tid * 8;
  bf16* lA1 = As + 2048 + tid * 8;
  bf16* lB0 = Bs + tid * 8;
  bf16* lB1 = Bs + 2048 + tid * 8;
  int kbeg = blockIdx.z * Kseg;
  int kend = kbeg + Kseg;
  for (int k0 = kbeg; k0 < kend; k0 += 32) {
    GLOAD_LDS16(Ap0 + k0, lA0);
    GLOAD_LDS16(Ap1 + k0, lA1);
    GLOAD_LDS16(Bp0 + k0, lB0);
    GLOAD_LDS16(Bp1 + k0, lB1);
    __syncthreads();
    bf16x8 af[4], bfv[4];
#pragma unroll
    for (int m = 0; m < 4; ++m) af[m] = *(const bf16x8*)(As + (wr * 64 + m * 16 + lr) * 32 + g * 8);
#pragma unroll
    for (int n = 0; n < 4; ++n) bfv[n] = *(const bf16x8*)(Bs + (wc * 64 + n * 16 + lr) * 32 + g * 8);
#pragma unroll
    for (int m = 0; m < 4; ++m)
#pragma unroll
      for (int n = 0; n < 4; ++n) acc[m][n] = MFMA(af[m], bfv[n], acc[m][n]);
    __syncthreads();
  }
  float* po = outf + (size_t)blockIdx.z * M * N;
#pragma unroll
  for (int m = 0; m < 4; ++m) {
#pragma unroll
    for (int n = 0; n < 4; ++n) {
      int rg0 = by * 128 + wr * 64 + m * 16 + g * 4;
      int cg = bx * 128 + wc * 64 + n * 16 + lr;
#pragma unroll
      for (int j = 0; j < 4; ++j) po[(size_t)(rg0 + j) * N + cg] = acc[m][n][j];
    }
  }
}

// ---------------- split-K reduce: out = res*w + sum(parts) + bias ----------------
template <int SK>
__global__ __launch_bounds__(256) void reduce_add(const float* __restrict__ part,
                                                  const float* __restrict__ bias,
                                                  const float* __restrict__ res,
                                                  const float* __restrict__ wsc,
                                                  float* __restrict__ out, int MN, int N) {
  size_t i = ((size_t)blockIdx.x * 256 + threadIdx.x) * 4;
  float4 a = *(const float4*)(part + i);
#pragma unroll
  for (int s = 1; s < SK; ++s) {
    float4 b = *(const float4*)(part + (size_t)s * MN + i);
    a.x += b.x; a.y += b.y; a.z += b.z; a.w += b.w;
  }
  int col = (int)(i & (size_t)(N - 1));
  float4 bv = *(const float4*)(bias + col);
  float4 rv = *(const float4*)(res + i);
  float w = wsc[0];
  float4 o;
  o.x = rv.x * w + a.x + bv.x;
  o.y = rv.y * w + a.y + bv.y;
  o.z = rv.z * w + a.z + bv.z;
  o.w = rv.w * w + a.w + bv.w;
  *(float4*)(out + i) = o;
}

// ---------------- fused proj split-K reduce + residual + LayerNorm2 ----------------
__global__ __launch_bounds__(256) void reduce_ln(const float* __restrict__ part,
                                                 const float* __restrict__ bias,
                                                 const float* __restrict__ res,
                                                 const float* __restrict__ wsc,
                                                 const float* __restrict__ lng,
                                                 const float* __restrict__ lnb,
                                                 float* __restrict__ x2out,
                                                 bf16* __restrict__ lnout) {
  int row = blockIdx.x, tid = threadIdx.x;
  size_t i = ((size_t)row << 10) + tid * 4;
  float4 a = *(const float4*)(part + i);
  float4 b2 = *(const float4*)(part + 4194304 + i);
  float4 rv = *(const float4*)(res + i);
  float4 bv = *(const float4*)(bias + tid * 4);
  float w = wsc[0];
  float4 o;
  o.x = rv.x * w + a.x + b2.x + bv.x;
  o.y = rv.y * w + a.y + b2.y + bv.y;
  o.z = rv.z * w + a.z + b2.z + bv.z;
  o.w = rv.w * w + a.w + b2.w + bv.w;
  *(float4*)(x2out + i) = o;
  float s = o.x + o.y + o.z + o.w;
  float ss = o.x * o.x + o.y * o.y + o.z * o.z + o.w * o.w;
#pragma unroll
  for (int off = 32; off >= 1; off >>= 1) {
    s += __shfl_down(s, off);
    ss += __shfl_down(ss, off);
  }
  __shared__ float sh[8];
  int wid = tid >> 6;
  if ((tid & 63) == 0) { sh[wid] = s; sh[wid + 4] = ss; }
  __syncthreads();
  float ts = sh[0] + sh[1] + sh[2] + sh[3];
  float tss = sh[4] + sh[5] + sh[6] + sh[7];
  float mean = ts * (1.0f / 1024.0f);
  float var = tss * (1.0f / 1024.0f) - mean * mean;
  float inv = rsqrtf(var + 1e-5f);
  float4 gg = *(const float4*)(lng + tid * 4);
  float4 bb = *(const float4*)(lnb + tid * 4);
  bf16x4 ov;
  ov[0] = (bf16)((o.x - mean) * inv * gg.x + bb.x);
  ov[1] = (bf16)((o.y - mean) * inv * gg.y + bb.y);
  ov[2] = (bf16)((o.z - mean) * inv * gg.z + bb.z);
  ov[3] = (bf16)((o.w - mean) * inv * gg.w + bb.w);
  *(bf16x4*)(lnout + ((size_t)row << 10) + tid * 4) = ov;
}

// ---------------- V transpose from qkv: vT[bh][d][t] ----------------
__global__ __launch_bounds__(256) void split_v_t(const bf16* __restrict__ qkv,
                                                 bf16* __restrict__ vT) {
  int t0 = blockIdx.x * 32;
  int bh = blockIdx.y;
  int b = bh >> 4, h = bh & 15;
  __shared__ bf16 tile[32][72];
  int tid = threadIdx.x;
  int d = tid & 63, tl0 = tid >> 6;
#pragma unroll
  for (int p = 0; p < 8; ++p) {
    int tl = p * 4 + tl0;
    tile[tl][d] = qkv[((size_t)(b * 2048 + t0 + tl)) * 3072 + 2048 + h * 64 + d];
  }
  __syncthreads();
  int tl = tid & 31, dq = tid >> 5;
#pragma unroll
  for (int p = 0; p < 8; ++p) {
    int dd = p * 8 + dq;
    vT[((size_t)(bh * 64 + dd)) * 2048 + t0 + tl] = tile[tl][dd];
  }
}

// ---------------- flash attention fwd (LDS-staged K/V, double-buffered, split-K=2) ----------------
__global__ __launch_bounds__(256) void attn_fwd(const bf16* __restrict__ qkv,
                                                const bf16* __restrict__ vT,
                                                float* __restrict__ o_part,
                                                float* __restrict__ ml_part) {
  __shared__ __align__(16) bf16 Ks[2][4096];
  __shared__ __align__(16) bf16 Vs[2][4096];
  __shared__ bf16 P[4][16][72];
  int id = blockIdx.x;            // 0..2047
  int bh = id & 31;
  int seg = (id >> 5) & 1;
  int qi = ((id >> 6) + bh) & 31; // stagger causal depth
  int tid = threadIdx.x, wid = tid >> 6, lane = tid & 63;
  int g = lane >> 4, lr = lane & 15;
  int b = bh >> 4, h = bh & 15;
  int nk = qi + 1;
  int n0 = (nk + 1) >> 1;
  int kt0 = seg ? n0 : 0;
  int kt1 = seg ? nk : n0;
  int qrow = qi * 64 + wid * 16 + lr;
  const bf16* Qr = qkv + ((size_t)(b * 2048 + qrow)) * 3072 + h * 64;
  bf16x8 qf[2];
  qf[0] = *(const bf16x8*)(Qr + g * 8);
  qf[1] = *(const bf16x8*)(Qr + 32 + g * 8);
  int r0 = tid >> 3, cs0 = ((tid & 7) ^ (r0 & 7)) << 3;
  int c1i = tid + 256;
  int r1 = c1i >> 3, cs1 = ((c1i & 7) ^ (r1 & 7)) << 3;
  const bf16* sK0 = qkv + ((size_t)(b * 2048 + r0)) * 3072 + 1024 + h * 64 + cs0;
  const bf16* sK1 = qkv + ((size_t)(b * 2048 + r1)) * 3072 + 1024 + h * 64 + cs1;
  const bf16* sV0 = vT + (size_t)bh * 131072 + (size_t)r0 * 2048 + cs0;
  const bf16* sV1 = vT + (size_t)bh * 131072 + (size_t)r1 * 2048 + cs1;
  bf16* dK0 = &Ks[0][0] + tid * 8;
  bf16* dK1 = &Ks[0][0] + 2048 + tid * 8;
  bf16* dV0 = &Vs[0][0] + tid * 8;
  bf16* dV1 = &Vs[0][0] + 2048 + tid * 8;
#define ATTN_STAGE(bufsel, ktv)                          \
  {                                                      \
    size_t kadv = (size_t)(ktv) * (64 * 3072);           \
    size_t vadv = (size_t)(ktv) * 64;                    \
    int bo = (bufsel) * 4096;                            \
    GLOAD_LDS16(sK0 + kadv, dK0 + bo);                   \
    GLOAD_LDS16(sK1 + kadv, dK1 + bo);                   \
    GLOAD_LDS16(sV0 + vadv, dV0 + bo);                   \
    GLOAD_LDS16(sV1 + vadv, dV1 + bo);                   \
  }
  f32x4 o[4];
#pragma unroll
  for (int n = 0; n < 4; ++n) o[n] = (f32x4){0.f, 0.f, 0.f, 0.f};
  float m = -3e38f, l = 0.f;
  if (kt0 < kt1) ATTN_STAGE(0, kt0);
  __syncthreads();
  const float beta = 0.18033688f;  // 0.125 * log2(e)
  int sw = lr & 7;
  int sb = (lane & 48) | (g << 2);
  for (int kt = kt0; kt < kt1; ++kt) {
    int cur = (kt - kt0) & 1;
    if (kt + 1 < kt1) ATTN_STAGE(cur ^ 1, kt + 1);
    const bf16* Kb = &Ks[cur][0];
    const bf16* Vb = &Vs[cur][0];
    f32x4 s[4];
#pragma unroll
    for (int n = 0; n < 4; ++n) s[n] = (f32x4){0.f, 0.f, 0.f, 0.f};
#pragma unroll
    for (int kk = 0; kk < 2; ++kk) {
#pragma unroll
      for (int n = 0; n < 4; ++n) {
        bf16x8 kf = *(const bf16x8*)(Kb + ((n * 16 + lr) << 6) + ((((kk << 2) + g) ^ sw) << 3));
        s[n] = MFMA(kf, qf[kk], s[n]);
      }
    }
    int kc0 = kt * 64 + g * 4;
#pragma unroll
    for (int n = 0; n < 4; ++n)
#pragma unroll
      for (int j = 0; j < 4; ++j) {
        float sv = s[n][j] * beta;
        s[n][j] = ((kc0 + n * 16 + j) <= qrow) ? sv : -3e38f;
      }
    float mx = s[0][0];
#pragma unroll
    for (int n = 0; n < 4; ++n)
#pragma unroll
      for (int j = 0; j < 4; ++j) mx = fmaxf(mx, s[n][j]);
    mx = fmaxf(mx, __shfl_xor(mx, 16));
    mx = fmaxf(mx, __shfl_xor(mx, 32));
    float mn = fmaxf(m, mx);
    float al = exp2f(m - mn);
    m = mn;
    float rs = 0.f;
    bf16x4 pw[4];
#pragma unroll
    for (int n = 0; n < 4; ++n)
#pragma unroll
      for (int j = 0; j < 4; ++j) {
        float p = exp2f(s[n][j] - mn);
        rs += p;
        pw[n][j] = (bf16)p;
      }
    rs += __shfl_xor(rs, 16);
    rs += __shfl_xor(rs, 32);
    l = l * al + rs;
    float alj[4];
#pragma unroll
    for (int j = 0; j < 4; ++j) alj[j] = __shfl(al, sb + j);
#pragma unroll
    for (int n = 0; n < 4; ++n)
#pragma unroll
      for (int j = 0; j < 4; ++j) o[n][j] *= alj[j];
#pragma unroll
    for (int n = 0; n < 4; ++n) *(bf16x4*)&P[wid][lr][n * 16 + g * 4] = pw[n];
#pragma unroll
    for (int kk = 0; kk < 2; ++kk) {
      bf16x8 pf = *(const bf16x8*)&P[wid][lr][kk * 32 + g * 8];
#pragma unroll
      for (int n = 0; n < 4; ++n) {
        bf16x8 vf = *(const bf16x8*)(Vb + ((n * 16 + lr) << 6) + ((((kk << 2) + g) ^ sw) << 3));
        o[n] = MFMA(pf, vf, o[n]);
      }
    }
    __syncthreads();
  }
  float* ob = o_part + (size_t)id * 4096;
#pragma unroll
  for (int n = 0; n < 4; ++n)
#pragma unroll
    for (int j = 0; j < 4; ++j)
      ob[(size_t)(wid * 16 + g * 4 + j) * 64 + n * 16 + lr] = o[n][j];
  if (lane < 16) {
    ml_part[(size_t)id * 128 + (wid * 16 + lane) * 2] = m;
    ml_part[(size_t)id * 128 + (wid * 16 + lane) * 2 + 1] = l;
  }
#undef ATTN_STAGE
}

// ---------------- attention combine ----------------
__global__ __launch_bounds__(256) void attn_combine(const float* __restrict__ o_part,
                                                    const float* __restrict__ ml_part,
                                                    bf16* __restrict__ y) {
  int c = blockIdx.x;  // 0..1023: (bh, qi)
  int bh = c & 31, qi = c >> 5;
  int b = bh >> 4, h = bh & 15;
  int qraw = (qi - bh) & 31;
  size_t id0 = (size_t)bh + ((size_t)qraw << 6);
  size_t id1 = id0 + 32;
  int t = threadIdx.x;
  int r = t >> 2, cq = (t & 3) << 4;
  float m1 = ml_part[id0 * 128 + r * 2], l1 = ml_part[id0 * 128 + r * 2 + 1];
  float m2 = ml_part[id1 * 128 + r * 2], l2 = ml_part[id1 * 128 + r * 2 + 1];
  float mm = fmaxf(m1, m2);
  float w1 = exp2f(m1 - mm), w2 = exp2f(m2 - mm);
  float inv = 1.0f / (l1 * w1 + l2 * w2);
  const float* p1 = o_part + id0 * 4096 + r * 64 + cq;
  const float* p2 = o_part + id1 * 4096 + r * 64 + cq;
  bf16* yp = y + ((size_t)(b * 2048 + qi * 64 + r)) * 1024 + h * 64 + cq;
#pragma unroll
  for (int u = 0; u < 4; ++u) {
    float4 a = *(const float4*)(p1 + u * 4);
    float4 bq = *(const float4*)(p2 + u * 4);
    bf16x4 ov;
    ov[0] = (bf16)((a.x * w1 + bq.x * w2) * inv);
    ov[1] = (bf16)((a.y * w1 + bq.y * w2) * inv);
    ov[2] = (bf16)((a.z * w1 + bq.z * w2) * inv);
    ov[3] = (bf16)((a.w * w1 + bq.w * w2) * inv);
    *(bf16x4*)(yp + u * 4) = ov;
  }
}

// ---------------- launch ----------------
extern "C" void kernel_launch(void* const* d_in, const int* in_sizes, int n_in,
                              void* d_out, int out_size, void* d_ws, size_t ws_size,
                              hipStream_t stream) {
  const float* x = (const float*)d_in[0];
  const float* ln1_g = (const float*)d_in[1];
  const float* ln1_b = (const float*)d_in[2];
  const float* attn_w = (const float*)d_in[3];
  const float* attn_b = (const float*)d_in[4];
  const float* proj_w = (const float*)d_in[5];
  const float* proj_b = (const float*)d_in[6];
  const float* ln2_g = (const float*)d_in[7];
  const float* ln2_b = (const float*)d_in[8];
  const float* mlp_w1 = (const float*)d_in[9];
  const float* mlp_b1 = (const float*)d_in[10];
  const float* mlp_w2 = (const float*)d_in[11];
  const float* mlp_b2 = (const float*)d_in[12];
  const float* w_att = (const float*)d_in[13];
  const float* w_mlp = (const float*)d_in[14];
  float* out = (float*)d_out;

  unsigned char* base = nullptr;
  if (ws_size >= TOTAL_BYTES) {
    base = (unsigned char*)d_ws;
  } else {
    hipGetSymbolAddress((void**)&base, HIP_SYMBOL(g_buf));
  }
  bf16* bb = (bf16*)base;
  bf16* wt_attn = bb + E_WT_ATTN;
  bf16* wt_proj = bb + E_WT_PROJ;
  bf16* wt_mlp1 = bb + E_WT_MLP1;
  bf16* wt_mlp2 = bb + E_WT_MLP2;
  bf16* ln1o = bb + E_LN1;
  bf16* qkv = bb + E_QKV;
  bf16* vTb = bb + E_VT;
  bf16* yb = bb + E_Y;
  bf16* ln2o = bb + E_LN2;
  bf16* hb = bb + E_H;
  float* x2 = (float*)(base + BYTE_X2);
  float* o_part = (float*)(base + BYTE_OPART);
  float* ml_part = (float*)(base + BYTE_ML);
  float* gpart = (float*)(base + BYTE_GPART);

  dim3 tb(32, 8);
  transpose_cast<<<dim3(3072 / 32, 1024 / 32), tb, 0, stream>>>(attn_w, wt_attn, 1024, 3072);
  transpose_cast<<<dim3(1024 / 32, 1024 / 32), tb, 0, stream>>>(proj_w, wt_proj, 1024, 1024);
  transpose_cast<<<dim3(4096 / 32, 1024 / 32), tb, 0, stream>>>(mlp_w1, wt_mlp1, 1024, 4096);
  transpose_cast<<<dim3(1024 / 32, 4096 / 32), tb, 0, stream>>>(mlp_w2, wt_mlp2, 4096, 1024);

  ln_bf16<<<4096, 256, 0, stream>>>(x, ln1_g, ln1_b, ln1o);

  gemm256<0><<<dim3(12, 16, 1), 512, 0, stream>>>(ln1o, wt_attn, attn_b, qkv, nullptr,
                                                  4096, 3072, 1024, 1024);

  split_v_t<<<dim3(64, 32), 256, 0, stream>>>(qkv, vTb);

  attn_fwd<<<2048, 256, 0, stream>>>(qkv, vTb, o_part, ml_part);
  attn_combine<<<1024, 256, 0, stream>>>(o_part, ml_part, yb);

  gemm_bt3<<<dim3(8, 32, 2), 256, 0, stream>>>(yb, wt_proj, gpart, 4096, 1024, 1024, 512);
  reduce_ln<<<4096, 256, 0, stream>>>(gpart, proj_b, x, w_att, ln2_g, ln2_b, x2, ln2o);

  gemm256<1><<<dim3(16, 16, 1), 512, 0, stream>>>(ln2o, wt_mlp1, mlp_b1, hb, nullptr,
                                                  4096, 4096, 1024, 1024);

  gemm256<3><<<dim3(4, 16, 4), 512, 0, stream>>>(hb, wt_mlp2, nullptr, nullptr, gpart,
                                                 4096, 1024, 4096, 1024);
  reduce_add<4><<<4096, 256, 0, stream>>>(gpart, mlp_b2, x2, w_mlp, out, 4194304, 1024);
}

// Round 7
// 385.225 us; speedup vs baseline: 1.6023x; 1.0487x over previous
//
#include <hip/hip_runtime.h>
#include <math.h>

typedef __bf16 bf16;
typedef bf16 bf16x8 __attribute__((ext_vector_type(8)));
typedef bf16 bf16x4 __attribute__((ext_vector_type(4)));
typedef float f32x4 __attribute__((ext_vector_type(4)));

#define MFMA(a, b, c) __builtin_amdgcn_mfma_f32_16x16x32_bf16((a), (b), (c), 0, 0, 0)

#define GLOAD_LDS16(gp, lp)                                                        \
  __builtin_amdgcn_global_load_lds((const __attribute__((address_space(1))) void*)(gp), \
                                   (__attribute__((address_space(3))) void*)(lp), 16, 0, 0)

// ---------------- workspace layout ----------------
// bf16 element offsets
static const size_t E_WT_ATTN = 0;          // [3072][1024]
static const size_t E_WT_PROJ = 3145728;    // [1024][1024]
static const size_t E_WT_MLP1 = 4194304;    // [4096][1024]
static const size_t E_WT_MLP2 = 8388608;    // [1024][4096]
static const size_t E_LN1     = 12582912;   // [4096][1024]
static const size_t E_QKV     = 16777216;   // [4096][3072]
static const size_t E_VT      = 37748736;   // [B,H,64,T]
static const size_t E_Y       = 41943040;   // [4096][1024]
static const size_t E_LN2     = 46137344;   // [4096][1024]
static const size_t E_H       = 50331648;   // [4096][4096]
// byte offsets
static const size_t BYTE_X2    = 134217728; // float [4096][1024]
static const size_t BYTE_OPART = 150994944; // float [2048][64][64] attn partials
static const size_t BYTE_ML    = 184549376; // float [2048][64][2]
static const size_t BYTE_GPART = 185597952; // float [4][4096][1024] gemm split-K partials
static const size_t TOTAL_BYTES = 252706816;

__device__ __align__(4096) unsigned char g_buf[TOTAL_BYTES];

// ---------------- merged transpose+cast for all 4 weights ----------------
// f32 [K][N] -> bf16 [N][K]
__global__ __launch_bounds__(256) void transpose_all(const float* __restrict__ aw,
                                                     const float* __restrict__ pw,
                                                     const float* __restrict__ m1,
                                                     const float* __restrict__ m2,
                                                     bf16* __restrict__ o_a,
                                                     bf16* __restrict__ o_p,
                                                     bf16* __restrict__ o_m1,
                                                     bf16* __restrict__ o_m2) {
  __shared__ float tile[32][33];
  int bid = blockIdx.x;
  const float* in;
  bf16* out;
  int K, N, tix;
  if (bid < 3072) { in = aw; out = o_a; K = 1024; N = 3072; tix = bid; }
  else if (bid < 4096) { in = pw; out = o_p; K = 1024; N = 1024; tix = bid - 3072; }
  else if (bid < 8192) { in = m1; out = o_m1; K = 1024; N = 4096; tix = bid - 4096; }
  else { in = m2; out = o_m2; K = 4096; N = 1024; tix = bid - 8192; }
  int ntx = N >> 5;
  int bx = tix % ntx, by = tix / ntx;
  int tx = threadIdx.x, ty = threadIdx.y;
#pragma unroll
  for (int i = ty; i < 32; i += 8)
    tile[i][tx] = in[(size_t)(by * 32 + i) * N + bx * 32 + tx];
  __syncthreads();
#pragma unroll
  for (int i = ty; i < 32; i += 8)
    out[(size_t)(bx * 32 + i) * K + by * 32 + tx] = (bf16)tile[tx][i];
}

// ---------------- LayerNorm f32 row(1024) -> bf16 ----------------
__global__ __launch_bounds__(256) void ln_bf16(const float* __restrict__ x,
                                               const float* __restrict__ g,
                                               const float* __restrict__ b,
                                               bf16* __restrict__ out) {
  int row = blockIdx.x, tid = threadIdx.x;
  const float* xr = x + ((size_t)row << 10);
  float4 v = *(const float4*)(xr + tid * 4);
  float s = v.x + v.y + v.z + v.w;
  float ss = v.x * v.x + v.y * v.y + v.z * v.z + v.w * v.w;
#pragma unroll
  for (int off = 32; off >= 1; off >>= 1) {
    s += __shfl_down(s, off);
    ss += __shfl_down(ss, off);
  }
  __shared__ float sh[8];
  int wid = tid >> 6;
  if ((tid & 63) == 0) { sh[wid] = s; sh[wid + 4] = ss; }
  __syncthreads();
  float ts = sh[0] + sh[1] + sh[2] + sh[3];
  float tss = sh[4] + sh[5] + sh[6] + sh[7];
  float mean = ts * (1.0f / 1024.0f);
  float var = tss * (1.0f / 1024.0f) - mean * mean;
  float inv = rsqrtf(var + 1e-5f);
  float4 gg = *(const float4*)(g + tid * 4);
  float4 bb = *(const float4*)(b + tid * 4);
  bf16x4 o;
  o[0] = (bf16)((v.x - mean) * inv * gg.x + bb.x);
  o[1] = (bf16)((v.y - mean) * inv * gg.y + bb.y);
  o[2] = (bf16)((v.z - mean) * inv * gg.z + bb.z);
  o[3] = (bf16)((v.w - mean) * inv * gg.w + bb.w);
  *(bf16x4*)(out + ((size_t)row << 10) + tid * 4) = o;
}

// ---------------- 256x256 GEMM, BK=64, 8 waves, dbuf LDS, swizzled ----------------
// C[M][N] = A[M][K] @ Bt[N][K]^T. EPI 0: bf16(acc+bias); 1: bf16(gelu(acc+bias));
// 3: outf[z*M*N+idx] = acc (split-K partial)
template <int EPI>
__global__ __launch_bounds__(512, 2) void gemm256(const bf16* __restrict__ A,
                                                  const bf16* __restrict__ Bt,
                                                  const float* __restrict__ bias,
                                                  bf16* __restrict__ outb,
                                                  float* __restrict__ outf,
                                                  int M, int N, int K, int Kseg) {
  __shared__ __align__(16) bf16 As[2][16384];  // [buf][256*64]
  __shared__ __align__(16) bf16 Bs[2][16384];
  int tid = threadIdx.x;
  // XCD-contiguous tile remap (nwg % 8 == 0 for all our grids)
  int nwg = gridDim.x * gridDim.y;
  int bid = blockIdx.y * gridDim.x + blockIdx.x;
  int id2 = ((nwg & 7) == 0) ? ((bid & 7) * (nwg >> 3) + (bid >> 3)) : bid;
  int bx = id2 % gridDim.x, by = id2 / gridDim.x;
  int lane = tid & 63, wid = tid >> 6;
  int wr = wid >> 2, wc = wid & 3;  // 2 x 4 waves
  int g = lane >> 4, lr = lane & 15;
  f32x4 acc[8][4];
#pragma unroll
  for (int m = 0; m < 8; ++m)
#pragma unroll
    for (int n = 0; n < 4; ++n) acc[m][n] = (f32x4){0.f, 0.f, 0.f, 0.f};
  const bf16* Ab = A + (size_t)by * 256 * K;
  const bf16* Bb = Bt + (size_t)bx * 256 * K;
  int rbase = tid >> 3;
  int srccol = (((tid & 7) ^ (rbase & 7)) << 3);
  const bf16* Asrc = Ab + (size_t)rbase * K + srccol;
  const bf16* Bsrc = Bb + (size_t)rbase * K + srccol;
#define G256_STAGE(buf, k0)                                                \
  {                                                                        \
    _Pragma("unroll") for (int q = 0; q < 4; ++q) {                        \
      GLOAD_LDS16(Asrc + (size_t)(q * 64) * K + (k0), &As[buf][tid * 8 + q * 4096]); \
      GLOAD_LDS16(Bsrc + (size_t)(q * 64) * K + (k0), &Bs[buf][tid * 8 + q * 4096]); \
    }                                                                      \
  }
  int kbeg = blockIdx.z * Kseg;
  int NT = Kseg >> 6;
  G256_STAGE(0, kbeg);
  __syncthreads();
  int c = 0;
  for (int t = 0; t < NT; ++t) {
    if (t + 1 < NT) G256_STAGE(c ^ 1, kbeg + (t + 1) * 64);
#pragma unroll
    for (int kk = 0; kk < 2; ++kk) {
      bf16x8 af[8], bfv[4];
#pragma unroll
      for (int m = 0; m < 8; ++m) {
        int row = wr * 128 + m * 16 + lr;
        af[m] = *(const bf16x8*)&As[c][row * 64 + ((((kk << 2) + g) ^ (row & 7)) << 3)];
      }
#pragma unroll
      for (int n = 0; n < 4; ++n) {
        int row = wc * 64 + n * 16 + lr;
        bfv[n] = *(const bf16x8*)&Bs[c][row * 64 + ((((kk << 2) + g) ^ (row & 7)) << 3)];
      }
#pragma unroll
      for (int m = 0; m < 8; ++m)
#pragma unroll
        for (int n = 0; n < 4; ++n) acc[m][n] = MFMA(af[m], bfv[n], acc[m][n]);
    }
    __syncthreads();
    c ^= 1;
  }
#undef G256_STAGE
  if (EPI == 3) {
    float* po = outf + (size_t)blockIdx.z * M * N;
#pragma unroll
    for (int m = 0; m < 8; ++m) {
#pragma unroll
      for (int n = 0; n < 4; ++n) {
        int rg0 = by * 256 + wr * 128 + m * 16 + g * 4;
        int cg = bx * 256 + wc * 64 + n * 16 + lr;
#pragma unroll
        for (int j = 0; j < 4; ++j) po[(size_t)(rg0 + j) * N + cg] = acc[m][n][j];
      }
    }
  } else {
#pragma unroll
    for (int m = 0; m < 8; ++m) {
#pragma unroll
      for (int n = 0; n < 4; ++n) {
        int rg0 = by * 256 + wr * 128 + m * 16 + g * 4;
        int cg = bx * 256 + wc * 64 + n * 16 + lr;
        float bv = bias[cg];
#pragma unroll
        for (int j = 0; j < 4; ++j) {
          float v = acc[m][n][j] + bv;
          size_t idx = (size_t)(rg0 + j) * N + cg;
          if (EPI == 0)
            outb[idx] = (bf16)v;
          else {
            // exact-gelu via tanh form (branch-free, |err|<0.003)
            float u = 0.7978845608f * (v + 0.044715f * v * v * v);
            float e = exp2f(u * 2.885390082f);  // exp(2u)
            float th = 1.0f - 2.0f / (e + 1.0f);
            outb[idx] = (bf16)(0.5f * v * (1.0f + th));
          }
        }
      }
    }
  }
}

// ---------------- 128x128 GEMM (split-K partial only) ----------------
__global__ __launch_bounds__(256) void gemm_bt3(const bf16* __restrict__ A,
                                                const bf16* __restrict__ Bt,
                                                float* __restrict__ outf,
                                                int M, int N, int K, int Kseg) {
  __shared__ __align__(16) bf16 As[128 * 32];
  __shared__ __align__(16) bf16 Bs[128 * 32];
  int bx = blockIdx.x, by = blockIdx.y;
  int tid = threadIdx.x;
  int lane = tid & 63, wid = tid >> 6;
  int wr = wid >> 1, wc = wid & 1;
  int g = lane >> 4, lr = lane & 15;
  f32x4 acc[4][4];
#pragma unroll
  for (int m = 0; m < 4; ++m)
#pragma unroll
    for (int n = 0; n < 4; ++n) acc[m][n] = (f32x4){0.f, 0.f, 0.f, 0.f};
  const bf16* Ab = A + (size_t)by * 128 * K;
  const bf16* Bb = Bt + (size_t)bx * 128 * K;
  int srow = tid >> 2;
  int sk8 = (tid & 3) * 8;
  const bf16* Ap0 = Ab + (size_t)srow * K + sk8;
  const bf16* Ap1 = Ab + (size_t)(srow + 64) * K + sk8;
  const bf16* Bp0 = Bb + (size_t)srow * K + sk8;
  const bf16* Bp1 = Bb + (size_t)(srow + 64) * K + sk8;
  bf16* lA0 = As + tid * 8;
  bf16* lA1 = As + 2048 + tid * 8;
  bf16* lB0 = Bs + tid * 8;
  bf16* lB1 = Bs + 2048 + tid * 8;
  int kbeg = blockIdx.z * Kseg;
  int kend = kbeg + Kseg;
  for (int k0 = kbeg; k0 < kend; k0 += 32) {
    GLOAD_LDS16(Ap0 + k0, lA0);
    GLOAD_LDS16(Ap1 + k0, lA1);
    GLOAD_LDS16(Bp0 + k0, lB0);
    GLOAD_LDS16(Bp1 + k0, lB1);
    __syncthreads();
    bf16x8 af[4], bfv[4];
#pragma unroll
    for (int m = 0; m < 4; ++m) af[m] = *(const bf16x8*)(As + (wr * 64 + m * 16 + lr) * 32 + g * 8);
#pragma unroll
    for (int n = 0; n < 4; ++n) bfv[n] = *(const bf16x8*)(Bs + (wc * 64 + n * 16 + lr) * 32 + g * 8);
#pragma unroll
    for (int m = 0; m < 4; ++m)
#pragma unroll
      for (int n = 0; n < 4; ++n) acc[m][n] = MFMA(af[m], bfv[n], acc[m][n]);
    __syncthreads();
  }
  float* po = outf + (size_t)blockIdx.z * M * N;
#pragma unroll
  for (int m = 0; m < 4; ++m) {
#pragma unroll
    for (int n = 0; n < 4; ++n) {
      int rg0 = by * 128 + wr * 64 + m * 16 + g * 4;
      int cg = bx * 128 + wc * 64 + n * 16 + lr;
#pragma unroll
      for (int j = 0; j < 4; ++j) po[(size_t)(rg0 + j) * N + cg] = acc[m][n][j];
    }
  }
}

// ---------------- split-K reduce: out = res*w + sum(parts) + bias ----------------
template <int SK>
__global__ __launch_bounds__(256) void reduce_add(const float* __restrict__ part,
                                                  const float* __restrict__ bias,
                                                  const float* __restrict__ res,
                                                  const float* __restrict__ wsc,
                                                  float* __restrict__ out, int MN, int N) {
  size_t i = ((size_t)blockIdx.x * 256 + threadIdx.x) * 4;
  float4 a = *(const float4*)(part + i);
#pragma unroll
  for (int s = 1; s < SK; ++s) {
    float4 b = *(const float4*)(part + (size_t)s * MN + i);
    a.x += b.x; a.y += b.y; a.z += b.z; a.w += b.w;
  }
  int col = (int)(i & (size_t)(N - 1));
  float4 bv = *(const float4*)(bias + col);
  float4 rv = *(const float4*)(res + i);
  float w = wsc[0];
  float4 o;
  o.x = rv.x * w + a.x + bv.x;
  o.y = rv.y * w + a.y + bv.y;
  o.z = rv.z * w + a.z + bv.z;
  o.w = rv.w * w + a.w + bv.w;
  *(float4*)(out + i) = o;
}

// ---------------- fused proj split-K reduce + residual + LayerNorm2 ----------------
__global__ __launch_bounds__(256) void reduce_ln(const float* __restrict__ part,
                                                 const float* __restrict__ bias,
                                                 const float* __restrict__ res,
                                                 const float* __restrict__ wsc,
                                                 const float* __restrict__ lng,
                                                 const float* __restrict__ lnb,
                                                 float* __restrict__ x2out,
                                                 bf16* __restrict__ lnout) {
  int row = blockIdx.x, tid = threadIdx.x;
  size_t i = ((size_t)row << 10) + tid * 4;
  float4 a = *(const float4*)(part + i);
  float4 b2 = *(const float4*)(part + 4194304 + i);
  float4 rv = *(const float4*)(res + i);
  float4 bv = *(const float4*)(bias + tid * 4);
  float w = wsc[0];
  float4 o;
  o.x = rv.x * w + a.x + b2.x + bv.x;
  o.y = rv.y * w + a.y + b2.y + bv.y;
  o.z = rv.z * w + a.z + b2.z + bv.z;
  o.w = rv.w * w + a.w + b2.w + bv.w;
  *(float4*)(x2out + i) = o;
  float s = o.x + o.y + o.z + o.w;
  float ss = o.x * o.x + o.y * o.y + o.z * o.z + o.w * o.w;
#pragma unroll
  for (int off = 32; off >= 1; off >>= 1) {
    s += __shfl_down(s, off);
    ss += __shfl_down(ss, off);
  }
  __shared__ float sh[8];
  int wid = tid >> 6;
  if ((tid & 63) == 0) { sh[wid] = s; sh[wid + 4] = ss; }
  __syncthreads();
  float ts = sh[0] + sh[1] + sh[2] + sh[3];
  float tss = sh[4] + sh[5] + sh[6] + sh[7];
  float mean = ts * (1.0f / 1024.0f);
  float var = tss * (1.0f / 1024.0f) - mean * mean;
  float inv = rsqrtf(var + 1e-5f);
  float4 gg = *(const float4*)(lng + tid * 4);
  float4 bb = *(const float4*)(lnb + tid * 4);
  bf16x4 ov;
  ov[0] = (bf16)((o.x - mean) * inv * gg.x + bb.x);
  ov[1] = (bf16)((o.y - mean) * inv * gg.y + bb.y);
  ov[2] = (bf16)((o.z - mean) * inv * gg.z + bb.z);
  ov[3] = (bf16)((o.w - mean) * inv * gg.w + bb.w);
  *(bf16x4*)(lnout + ((size_t)row << 10) + tid * 4) = ov;
}

// ---------------- V transpose from qkv: vT[bh][d][t] ----------------
__global__ __launch_bounds__(256) void split_v_t(const bf16* __restrict__ qkv,
                                                 bf16* __restrict__ vT) {
  int t0 = blockIdx.x * 32;
  int bh = blockIdx.y;
  int b = bh >> 4, h = bh & 15;
  __shared__ bf16 tile[32][72];
  int tid = threadIdx.x;
  int d = tid & 63, tl0 = tid >> 6;
#pragma unroll
  for (int p = 0; p < 8; ++p) {
    int tl = p * 4 + tl0;
    tile[tl][d] = qkv[((size_t)(b * 2048 + t0 + tl)) * 3072 + 2048 + h * 64 + d];
  }
  __syncthreads();
  int tl = tid & 31, dq = tid >> 5;
#pragma unroll
  for (int p = 0; p < 8; ++p) {
    int dd = p * 8 + dq;
    vT[((size_t)(bh * 64 + dd)) * 2048 + t0 + tl] = tile[tl][dd];
  }
}

// ---------------- flash attention fwd (LDS-staged K/V, dbuf, split-K=2, defer-max) ----------------
__global__ __launch_bounds__(256) void attn_fwd(const bf16* __restrict__ qkv,
                                                const bf16* __restrict__ vT,
                                                float* __restrict__ o_part,
                                                float* __restrict__ ml_part) {
  __shared__ __align__(16) bf16 Ks[2][4096];
  __shared__ __align__(16) bf16 Vs[2][4096];
  __shared__ bf16 P[4][16][72];
  int id = blockIdx.x;            // 0..2047
  int bh = id & 31;
  int seg = (id >> 5) & 1;
  int qi = ((id >> 6) + bh) & 31; // stagger causal depth
  int tid = threadIdx.x, wid = tid >> 6, lane = tid & 63;
  int g = lane >> 4, lr = lane & 15;
  int b = bh >> 4, h = bh & 15;
  int nk = qi + 1;
  int n0 = (nk + 1) >> 1;
  int kt0 = seg ? n0 : 0;
  int kt1 = seg ? nk : n0;
  int qrow = qi * 64 + wid * 16 + lr;
  const bf16* Qr = qkv + ((size_t)(b * 2048 + qrow)) * 3072 + h * 64;
  const float beta = 0.18033688f;  // 0.125 * log2(e): fold into Q
  bf16x8 qf[2];
  qf[0] = *(const bf16x8*)(Qr + g * 8);
  qf[1] = *(const bf16x8*)(Qr + 32 + g * 8);
#pragma unroll
  for (int kk = 0; kk < 2; ++kk)
#pragma unroll
    for (int e = 0; e < 8; ++e) qf[kk][e] = (bf16)((float)qf[kk][e] * beta);
  int r0 = tid >> 3, cs0 = ((tid & 7) ^ (r0 & 7)) << 3;
  int c1i = tid + 256;
  int r1 = c1i >> 3, cs1 = ((c1i & 7) ^ (r1 & 7)) << 3;
  const bf16* sK0 = qkv + ((size_t)(b * 2048 + r0)) * 3072 + 1024 + h * 64 + cs0;
  const bf16* sK1 = qkv + ((size_t)(b * 2048 + r1)) * 3072 + 1024 + h * 64 + cs1;
  const bf16* sV0 = vT + (size_t)bh * 131072 + (size_t)r0 * 2048 + cs0;
  const bf16* sV1 = vT + (size_t)bh * 131072 + (size_t)r1 * 2048 + cs1;
  bf16* dK0 = &Ks[0][0] + tid * 8;
  bf16* dK1 = &Ks[0][0] + 2048 + tid * 8;
  bf16* dV0 = &Vs[0][0] + tid * 8;
  bf16* dV1 = &Vs[0][0] + 2048 + tid * 8;
#define ATTN_STAGE(bufsel, ktv)                          \
  {                                                      \
    size_t kadv = (size_t)(ktv) * (64 * 3072);           \
    size_t vadv = (size_t)(ktv) * 64;                    \
    int bo = (bufsel) * 4096;                            \
    GLOAD_LDS16(sK0 + kadv, dK0 + bo);                   \
    GLOAD_LDS16(sK1 + kadv, dK1 + bo);                   \
    GLOAD_LDS16(sV0 + vadv, dV0 + bo);                   \
    GLOAD_LDS16(sV1 + vadv, dV1 + bo);                   \
  }
  f32x4 o[4];
#pragma unroll
  for (int n = 0; n < 4; ++n) o[n] = (f32x4){0.f, 0.f, 0.f, 0.f};
  float m = -3e38f, l = 0.f;
  if (kt0 < kt1) ATTN_STAGE(0, kt0);
  __syncthreads();
  int sw = lr & 7;
  int sb = (lane & 48) | (g << 2);
  for (int kt = kt0; kt < kt1; ++kt) {
    int cur = (kt - kt0) & 1;
    if (kt + 1 < kt1) ATTN_STAGE(cur ^ 1, kt + 1);
    const bf16* Kb = &Ks[cur][0];
    const bf16* Vb = &Vs[cur][0];
    f32x4 s[4];
#pragma unroll
    for (int n = 0; n < 4; ++n) s[n] = (f32x4){0.f, 0.f, 0.f, 0.f};
#pragma unroll
    for (int kk = 0; kk < 2; ++kk) {
#pragma unroll
      for (int n = 0; n < 4; ++n) {
        bf16x8 kf = *(const bf16x8*)(Kb + ((n * 16 + lr) << 6) + ((((kk << 2) + g) ^ sw) << 3));
        s[n] = MFMA(kf, qf[kk], s[n]);  // lane holds q-row lr, k-cols n*16+g*4+j (scaled)
      }
    }
    if (kt == qi) {  // diagonal tile only: causal mask (wave-uniform branch)
      int kc0 = kt * 64 + g * 4;
#pragma unroll
      for (int n = 0; n < 4; ++n)
#pragma unroll
        for (int j = 0; j < 4; ++j)
          if ((kc0 + n * 16 + j) > qrow) s[n][j] = -3e38f;
    }
    float mx = s[0][0];
#pragma unroll
    for (int n = 0; n < 4; ++n)
#pragma unroll
      for (int j = 0; j < 4; ++j) mx = fmaxf(mx, s[n][j]);
    mx = fmaxf(mx, __shfl_xor(mx, 16));
    mx = fmaxf(mx, __shfl_xor(mx, 32));
    // T13 defer-max: skip max-update + O-rescale when growth small (THR = 8*log2e)
    bool defer = __all(mx <= m + 11.5416f);
    float mn = m, al = 0.f;
    if (!defer) {
      mn = fmaxf(m, mx);
      al = exp2f(m - mn);
      m = mn;
    }
    float rs = 0.f;
    bf16x4 pw[4];
#pragma unroll
    for (int n = 0; n < 4; ++n)
#pragma unroll
      for (int j = 0; j < 4; ++j) {
        float p = exp2f(s[n][j] - mn);
        rs += p;
        pw[n][j] = (bf16)p;
      }
    rs += __shfl_xor(rs, 16);
    rs += __shfl_xor(rs, 32);
    if (defer) {
      l += rs;
    } else {
      l = l * al + rs;
      float alj[4];
#pragma unroll
      for (int j = 0; j < 4; ++j) alj[j] = __shfl(al, sb + j);
#pragma unroll
      for (int n = 0; n < 4; ++n)
#pragma unroll
        for (int j = 0; j < 4; ++j) o[n][j] *= alj[j];
    }
#pragma unroll
    for (int n = 0; n < 4; ++n) *(bf16x4*)&P[wid][lr][n * 16 + g * 4] = pw[n];
#pragma unroll
    for (int kk = 0; kk < 2; ++kk) {
      bf16x8 pf = *(const bf16x8*)&P[wid][lr][kk * 32 + g * 8];
#pragma unroll
      for (int n = 0; n < 4; ++n) {
        bf16x8 vf = *(const bf16x8*)(Vb + ((n * 16 + lr) << 6) + ((((kk << 2) + g) ^ sw) << 3));
        o[n] = MFMA(pf, vf, o[n]);
      }
    }
    __syncthreads();
  }
  float* ob = o_part + (size_t)id * 4096;
#pragma unroll
  for (int n = 0; n < 4; ++n)
#pragma unroll
    for (int j = 0; j < 4; ++j)
      ob[(size_t)(wid * 16 + g * 4 + j) * 64 + n * 16 + lr] = o[n][j];
  if (lane < 16) {
    ml_part[(size_t)id * 128 + (wid * 16 + lane) * 2] = m;
    ml_part[(size_t)id * 128 + (wid * 16 + lane) * 2 + 1] = l;
  }
#undef ATTN_STAGE
}

// ---------------- attention combine ----------------
__global__ __launch_bounds__(256) void attn_combine(const float* __restrict__ o_part,
                                                    const float* __restrict__ ml_part,
                                                    bf16* __restrict__ y) {
  int c = blockIdx.x;  // 0..1023: (bh, qi)
  int bh = c & 31, qi = c >> 5;
  int b = bh >> 4, h = bh & 15;
  int qraw = (qi - bh) & 31;
  size_t id0 = (size_t)bh + ((size_t)qraw << 6);
  size_t id1 = id0 + 32;
  int t = threadIdx.x;
  int r = t >> 2, cq = (t & 3) << 4;
  float m1 = ml_part[id0 * 128 + r * 2], l1 = ml_part[id0 * 128 + r * 2 + 1];
  float m2 = ml_part[id1 * 128 + r * 2], l2 = ml_part[id1 * 128 + r * 2 + 1];
  float mm = fmaxf(m1, m2);
  float w1 = exp2f(m1 - mm), w2 = exp2f(m2 - mm);
  float inv = 1.0f / (l1 * w1 + l2 * w2);
  const float* p1 = o_part + id0 * 4096 + r * 64 + cq;
  const float* p2 = o_part + id1 * 4096 + r * 64 + cq;
  bf16* yp = y + ((size_t)(b * 2048 + qi * 64 + r)) * 1024 + h * 64 + cq;
#pragma unroll
  for (int u = 0; u < 4; ++u) {
    float4 a = *(const float4*)(p1 + u * 4);
    float4 bq = *(const float4*)(p2 + u * 4);
    bf16x4 ov;
    ov[0] = (bf16)((a.x * w1 + bq.x * w2) * inv);
    ov[1] = (bf16)((a.y * w1 + bq.y * w2) * inv);
    ov[2] = (bf16)((a.z * w1 + bq.z * w2) * inv);
    ov[3] = (bf16)((a.w * w1 + bq.w * w2) * inv);
    *(bf16x4*)(yp + u * 4) = ov;
  }
}

// ---------------- launch ----------------
extern "C" void kernel_launch(void* const* d_in, const int* in_sizes, int n_in,
                              void* d_out, int out_size, void* d_ws, size_t ws_size,
                              hipStream_t stream) {
  const float* x = (const float*)d_in[0];
  const float* ln1_g = (const float*)d_in[1];
  const float* ln1_b = (const float*)d_in[2];
  const float* attn_w = (const float*)d_in[3];
  const float* attn_b = (const float*)d_in[4];
  const float* proj_w = (const float*)d_in[5];
  const float* proj_b = (const float*)d_in[6];
  const float* ln2_g = (const float*)d_in[7];
  const float* ln2_b = (const float*)d_in[8];
  const float* mlp_w1 = (const float*)d_in[9];
  const float* mlp_b1 = (const float*)d_in[10];
  const float* mlp_w2 = (const float*)d_in[11];
  const float* mlp_b2 = (const float*)d_in[12];
  const float* w_att = (const float*)d_in[13];
  const float* w_mlp = (const float*)d_in[14];
  float* out = (float*)d_out;

  unsigned char* base = nullptr;
  if (ws_size >= TOTAL_BYTES) {
    base = (unsigned char*)d_ws;
  } else {
    hipGetSymbolAddress((void**)&base, HIP_SYMBOL(g_buf));
  }
  bf16* bb = (bf16*)base;
  bf16* wt_attn = bb + E_WT_ATTN;
  bf16* wt_proj = bb + E_WT_PROJ;
  bf16* wt_mlp1 = bb + E_WT_MLP1;
  bf16* wt_mlp2 = bb + E_WT_MLP2;
  bf16* ln1o = bb + E_LN1;
  bf16* qkv = bb + E_QKV;
  bf16* vTb = bb + E_VT;
  bf16* yb = bb + E_Y;
  bf16* ln2o = bb + E_LN2;
  bf16* hb = bb + E_H;
  float* x2 = (float*)(base + BYTE_X2);
  float* o_part = (float*)(base + BYTE_OPART);
  float* ml_part = (float*)(base + BYTE_ML);
  float* gpart = (float*)(base + BYTE_GPART);

  transpose_all<<<12288, dim3(32, 8), 0, stream>>>(attn_w, proj_w, mlp_w1, mlp_w2,
                                                   wt_attn, wt_proj, wt_mlp1, wt_mlp2);

  ln_bf16<<<4096, 256, 0, stream>>>(x, ln1_g, ln1_b, ln1o);

  gemm256<0><<<dim3(12, 16, 1), 512, 0, stream>>>(ln1o, wt_attn, attn_b, qkv, nullptr,
                                                  4096, 3072, 1024, 1024);

  split_v_t<<<dim3(64, 32), 256, 0, stream>>>(qkv, vTb);

  attn_fwd<<<2048, 256, 0, stream>>>(qkv, vTb, o_part, ml_part);
  attn_combine<<<1024, 256, 0, stream>>>(o_part, ml_part, yb);

  gemm_bt3<<<dim3(8, 32, 2), 256, 0, stream>>>(yb, wt_proj, gpart, 4096, 1024, 1024, 512);
  reduce_ln<<<4096, 256, 0, stream>>>(gpart, proj_b, x, w_att, ln2_g, ln2_b, x2, ln2o);

  gemm256<1><<<dim3(16, 16, 1), 512, 0, stream>>>(ln2o, wt_mlp1, mlp_b1, hb, nullptr,
                                                  4096, 4096, 1024, 1024);

  gemm256<3><<<dim3(4, 16, 4), 512, 0, stream>>>(hb, wt_mlp2, nullptr, nullptr, gpart,
                                                 4096, 1024, 4096, 1024);
  reduce_add<4><<<4096, 256, 0, stream>>>(gpart, mlp_b2, x2, w_mlp, out, 4194304, 1024);
}

// Round 8
// 373.943 us; speedup vs baseline: 1.6507x; 1.0302x over previous
//
#include <hip/hip_runtime.h>
#include <math.h>

typedef __bf16 bf16;
typedef bf16 bf16x8 __attribute__((ext_vector_type(8)));
typedef bf16 bf16x4 __attribute__((ext_vector_type(4)));
typedef float f32x4 __attribute__((ext_vector_type(4)));

#define MFMA(a, b, c) __builtin_amdgcn_mfma_f32_16x16x32_bf16((a), (b), (c), 0, 0, 0)

#define GLOAD_LDS16(gp, lp)                                                        \
  __builtin_amdgcn_global_load_lds((const __attribute__((address_space(1))) void*)(gp), \
                                   (__attribute__((address_space(3))) void*)(lp), 16, 0, 0)

// ---------------- workspace layout ----------------
// bf16 element offsets
static const size_t E_WT_ATTN = 0;          // [3072][1024]
static const size_t E_WT_PROJ = 3145728;    // [1024][1024]
static const size_t E_WT_MLP1 = 4194304;    // [4096][1024]
static const size_t E_WT_MLP2 = 8388608;    // [1024][4096]
static const size_t E_LN1     = 12582912;   // [4096][1024]
static const size_t E_QKV     = 16777216;   // [4096][3072]
static const size_t E_VT      = 37748736;   // [B,H,64,T]
static const size_t E_Y       = 41943040;   // [4096][1024]
static const size_t E_LN2     = 46137344;   // [4096][1024]
static const size_t E_H       = 50331648;   // [4096][4096]
// byte offsets
static const size_t BYTE_X2    = 134217728; // float [4096][1024]
static const size_t BYTE_OPART = 150994944; // float [2048][64][64] attn partials
static const size_t BYTE_ML    = 184549376; // float [2048][64][2]
static const size_t BYTE_GPART = 185597952; // float [4][4096][1024] gemm split-K partials
static const size_t TOTAL_BYTES = 252706816;

__device__ __align__(4096) unsigned char g_buf[TOTAL_BYTES];

// ---------------- merged transpose+cast for all 4 weights ----------------
// f32 [K][N] -> bf16 [N][K]
__global__ __launch_bounds__(256) void transpose_all(const float* __restrict__ aw,
                                                     const float* __restrict__ pw,
                                                     const float* __restrict__ m1,
                                                     const float* __restrict__ m2,
                                                     bf16* __restrict__ o_a,
                                                     bf16* __restrict__ o_p,
                                                     bf16* __restrict__ o_m1,
                                                     bf16* __restrict__ o_m2) {
  __shared__ float tile[32][33];
  int bid = blockIdx.x;
  const float* in;
  bf16* out;
  int K, N, tix;
  if (bid < 3072) { in = aw; out = o_a; K = 1024; N = 3072; tix = bid; }
  else if (bid < 4096) { in = pw; out = o_p; K = 1024; N = 1024; tix = bid - 3072; }
  else if (bid < 8192) { in = m1; out = o_m1; K = 1024; N = 4096; tix = bid - 4096; }
  else { in = m2; out = o_m2; K = 4096; N = 1024; tix = bid - 8192; }
  int ntx = N >> 5;
  int bx = tix % ntx, by = tix / ntx;
  int tx = threadIdx.x, ty = threadIdx.y;
#pragma unroll
  for (int i = ty; i < 32; i += 8)
    tile[i][tx] = in[(size_t)(by * 32 + i) * N + bx * 32 + tx];
  __syncthreads();
#pragma unroll
  for (int i = ty; i < 32; i += 8)
    out[(size_t)(bx * 32 + i) * K + by * 32 + tx] = (bf16)tile[tx][i];
}

// ---------------- LayerNorm f32 row(1024) -> bf16 ----------------
__global__ __launch_bounds__(256) void ln_bf16(const float* __restrict__ x,
                                               const float* __restrict__ g,
                                               const float* __restrict__ b,
                                               bf16* __restrict__ out) {
  int row = blockIdx.x, tid = threadIdx.x;
  const float* xr = x + ((size_t)row << 10);
  float4 v = *(const float4*)(xr + tid * 4);
  float s = v.x + v.y + v.z + v.w;
  float ss = v.x * v.x + v.y * v.y + v.z * v.z + v.w * v.w;
#pragma unroll
  for (int off = 32; off >= 1; off >>= 1) {
    s += __shfl_down(s, off);
    ss += __shfl_down(ss, off);
  }
  __shared__ float sh[8];
  int wid = tid >> 6;
  if ((tid & 63) == 0) { sh[wid] = s; sh[wid + 4] = ss; }
  __syncthreads();
  float ts = sh[0] + sh[1] + sh[2] + sh[3];
  float tss = sh[4] + sh[5] + sh[6] + sh[7];
  float mean = ts * (1.0f / 1024.0f);
  float var = tss * (1.0f / 1024.0f) - mean * mean;
  float inv = rsqrtf(var + 1e-5f);
  float4 gg = *(const float4*)(g + tid * 4);
  float4 bb = *(const float4*)(b + tid * 4);
  bf16x4 o;
  o[0] = (bf16)((v.x - mean) * inv * gg.x + bb.x);
  o[1] = (bf16)((v.y - mean) * inv * gg.y + bb.y);
  o[2] = (bf16)((v.z - mean) * inv * gg.z + bb.z);
  o[3] = (bf16)((v.w - mean) * inv * gg.w + bb.w);
  *(bf16x4*)(out + ((size_t)row << 10) + tid * 4) = o;
}

// ---------------- 256x256 GEMM, BK=64, 8 waves, dbuf LDS, swizzled ----------------
// T4 counted-vmcnt pipeline: raw s_barrier + hand vmcnt/lgkmcnt, 2-deep prefetch.
// C[M][N] = A[M][K] @ Bt[N][K]^T. EPI 0: bf16(acc+bias); 1: bf16(gelu(acc+bias));
// 3: outf[z*M*N+idx] = acc (split-K partial)
template <int EPI>
__global__ __launch_bounds__(512, 2) void gemm256(const bf16* __restrict__ A,
                                                  const bf16* __restrict__ Bt,
                                                  const float* __restrict__ bias,
                                                  bf16* __restrict__ outb,
                                                  float* __restrict__ outf,
                                                  int M, int N, int K, int Kseg) {
  __shared__ __align__(16) bf16 As[2][16384];  // [buf][256*64]
  __shared__ __align__(16) bf16 Bs[2][16384];
  int tid = threadIdx.x;
  // XCD-contiguous tile remap (nwg % 8 == 0 for all our grids)
  int nwg = gridDim.x * gridDim.y;
  int bid = blockIdx.y * gridDim.x + blockIdx.x;
  int id2 = ((nwg & 7) == 0) ? ((bid & 7) * (nwg >> 3) + (bid >> 3)) : bid;
  int bx = id2 % gridDim.x, by = id2 / gridDim.x;
  int lane = tid & 63, wid = tid >> 6;
  int wr = wid >> 2, wc = wid & 3;  // 2 x 4 waves
  int g = lane >> 4, lr = lane & 15;
  f32x4 acc[8][4];
#pragma unroll
  for (int m = 0; m < 8; ++m)
#pragma unroll
    for (int n = 0; n < 4; ++n) acc[m][n] = (f32x4){0.f, 0.f, 0.f, 0.f};
  const bf16* Ab = A + (size_t)by * 256 * K;
  const bf16* Bb = Bt + (size_t)bx * 256 * K;
  int rbase = tid >> 3;
  int srccol = (((tid & 7) ^ (rbase & 7)) << 3);
  const bf16* Asrc = Ab + (size_t)rbase * K + srccol;
  const bf16* Bsrc = Bb + (size_t)rbase * K + srccol;
#define G256_STAGE(buf, k0)                                                \
  {                                                                        \
    _Pragma("unroll") for (int q = 0; q < 4; ++q) {                        \
      GLOAD_LDS16(Asrc + (size_t)(q * 64) * K + (k0), &As[buf][tid * 8 + q * 4096]); \
      GLOAD_LDS16(Bsrc + (size_t)(q * 64) * K + (k0), &Bs[buf][tid * 8 + q * 4096]); \
    }                                                                      \
  }
  int kbeg = blockIdx.z * Kseg;
  int NT = Kseg >> 6;
  // prologue: stage tiles 0 and 1; wait only for tile 0 (tile 1's 8 loads stay in flight)
  G256_STAGE(0, kbeg);
  if (NT > 1) {
    G256_STAGE(1, kbeg + 64);
    asm volatile("s_waitcnt vmcnt(8)" ::: "memory");
  } else {
    asm volatile("s_waitcnt vmcnt(0)" ::: "memory");
  }
  __builtin_amdgcn_sched_barrier(0);
  __builtin_amdgcn_s_barrier();
  int c = 0;
  for (int t = 0; t < NT; ++t) {
    bf16x8 a0[8], b0[4], a1[8], b1[4];
#pragma unroll
    for (int m = 0; m < 8; ++m) {
      int row = wr * 128 + m * 16 + lr;
      a0[m] = *(const bf16x8*)&As[c][row * 64 + ((g ^ (row & 7)) << 3)];
      a1[m] = *(const bf16x8*)&As[c][row * 64 + (((4 + g) ^ (row & 7)) << 3)];
    }
#pragma unroll
    for (int n = 0; n < 4; ++n) {
      int row = wc * 64 + n * 16 + lr;
      b0[n] = *(const bf16x8*)&Bs[c][row * 64 + ((g ^ (row & 7)) << 3)];
      b1[n] = *(const bf16x8*)&Bs[c][row * 64 + (((4 + g) ^ (row & 7)) << 3)];
    }
    // kk=0 MFMA cluster (compiler inserts its own lgkm waits for the frags)
#pragma unroll
    for (int m = 0; m < 8; ++m)
#pragma unroll
      for (int n = 0; n < 4; ++n) acc[m][n] = MFMA(a0[m], b0[n], acc[m][n]);
    // all ds_reads of buf c complete before anyone overwrites it
    asm volatile("s_waitcnt lgkmcnt(0)" ::: "memory");
    __builtin_amdgcn_sched_barrier(0);
    __builtin_amdgcn_s_barrier();
    if (t + 2 < NT) G256_STAGE(c, kbeg + (t + 2) * 64);  // overwrite c with tile t+2
    // kk=1 MFMA cluster (register operands; overlaps the staging loads)
#pragma unroll
    for (int m = 0; m < 8; ++m)
#pragma unroll
      for (int n = 0; n < 4; ++n) acc[m][n] = MFMA(a1[m], b1[n], acc[m][n]);
    // counted wait: retire tile t+1's 8 loads, keep tile t+2's 8 in flight
    if (t + 2 < NT) {
      asm volatile("s_waitcnt vmcnt(8)" ::: "memory");
    } else if (t + 1 < NT) {
      asm volatile("s_waitcnt vmcnt(0)" ::: "memory");
    }
    __builtin_amdgcn_sched_barrier(0);
    __builtin_amdgcn_s_barrier();  // tile t+1 fully resident in buf c^1
    c ^= 1;
  }
#undef G256_STAGE
  if (EPI == 3) {
    float* po = outf + (size_t)blockIdx.z * M * N;
#pragma unroll
    for (int m = 0; m < 8; ++m) {
#pragma unroll
      for (int n = 0; n < 4; ++n) {
        int rg0 = by * 256 + wr * 128 + m * 16 + g * 4;
        int cg = bx * 256 + wc * 64 + n * 16 + lr;
#pragma unroll
        for (int j = 0; j < 4; ++j) po[(size_t)(rg0 + j) * N + cg] = acc[m][n][j];
      }
    }
  } else {
#pragma unroll
    for (int m = 0; m < 8; ++m) {
#pragma unroll
      for (int n = 0; n < 4; ++n) {
        int rg0 = by * 256 + wr * 128 + m * 16 + g * 4;
        int cg = bx * 256 + wc * 64 + n * 16 + lr;
        float bv = bias[cg];
#pragma unroll
        for (int j = 0; j < 4; ++j) {
          float v = acc[m][n][j] + bv;
          size_t idx = (size_t)(rg0 + j) * N + cg;
          if (EPI == 0)
            outb[idx] = (bf16)v;
          else {
            // exact-gelu via tanh form (branch-free, |err|<0.003)
            float u = 0.7978845608f * (v + 0.044715f * v * v * v);
            float e = exp2f(u * 2.885390082f);  // exp(2u)
            float th = 1.0f - 2.0f / (e + 1.0f);
            outb[idx] = (bf16)(0.5f * v * (1.0f + th));
          }
        }
      }
    }
  }
}

// ---------------- 128x128 GEMM (split-K partial only) ----------------
__global__ __launch_bounds__(256) void gemm_bt3(const bf16* __restrict__ A,
                                                const bf16* __restrict__ Bt,
                                                float* __restrict__ outf,
                                                int M, int N, int K, int Kseg) {
  __shared__ __align__(16) bf16 As[128 * 32];
  __shared__ __align__(16) bf16 Bs[128 * 32];
  int bx = blockIdx.x, by = blockIdx.y;
  int tid = threadIdx.x;
  int lane = tid & 63, wid = tid >> 6;
  int wr = wid >> 1, wc = wid & 1;
  int g = lane >> 4, lr = lane & 15;
  f32x4 acc[4][4];
#pragma unroll
  for (int m = 0; m < 4; ++m)
#pragma unroll
    for (int n = 0; n < 4; ++n) acc[m][n] = (f32x4){0.f, 0.f, 0.f, 0.f};
  const bf16* Ab = A + (size_t)by * 128 * K;
  const bf16* Bb = Bt + (size_t)bx * 128 * K;
  int srow = tid >> 2;
  int sk8 = (tid & 3) * 8;
  const bf16* Ap0 = Ab + (size_t)srow * K + sk8;
  const bf16* Ap1 = Ab + (size_t)(srow + 64) * K + sk8;
  const bf16* Bp0 = Bb + (size_t)srow * K + sk8;
  const bf16* Bp1 = Bb + (size_t)(srow + 64) * K + sk8;
  bf16* lA0 = As + tid * 8;
  bf16* lA1 = As + 2048 + tid * 8;
  bf16* lB0 = Bs + tid * 8;
  bf16* lB1 = Bs + 2048 + tid * 8;
  int kbeg = blockIdx.z * Kseg;
  int kend = kbeg + Kseg;
  for (int k0 = kbeg; k0 < kend; k0 += 32) {
    GLOAD_LDS16(Ap0 + k0, lA0);
    GLOAD_LDS16(Ap1 + k0, lA1);
    GLOAD_LDS16(Bp0 + k0, lB0);
    GLOAD_LDS16(Bp1 + k0, lB1);
    __syncthreads();
    bf16x8 af[4], bfv[4];
#pragma unroll
    for (int m = 0; m < 4; ++m) af[m] = *(const bf16x8*)(As + (wr * 64 + m * 16 + lr) * 32 + g * 8);
#pragma unroll
    for (int n = 0; n < 4; ++n) bfv[n] = *(const bf16x8*)(Bs + (wc * 64 + n * 16 + lr) * 32 + g * 8);
#pragma unroll
    for (int m = 0; m < 4; ++m)
#pragma unroll
      for (int n = 0; n < 4; ++n) acc[m][n] = MFMA(af[m], bfv[n], acc[m][n]);
    __syncthreads();
  }
  float* po = outf + (size_t)blockIdx.z * M * N;
#pragma unroll
  for (int m = 0; m < 4; ++m) {
#pragma unroll
    for (int n = 0; n < 4; ++n) {
      int rg0 = by * 128 + wr * 64 + m * 16 + g * 4;
      int cg = bx * 128 + wc * 64 + n * 16 + lr;
#pragma unroll
      for (int j = 0; j < 4; ++j) po[(size_t)(rg0 + j) * N + cg] = acc[m][n][j];
    }
  }
}

// ---------------- split-K reduce: out = res*w + sum(parts) + bias ----------------
template <int SK>
__global__ __launch_bounds__(256) void reduce_add(const float* __restrict__ part,
                                                  const float* __restrict__ bias,
                                                  const float* __restrict__ res,
                                                  const float* __restrict__ wsc,
                                                  float* __restrict__ out, int MN, int N) {
  size_t i = ((size_t)blockIdx.x * 256 + threadIdx.x) * 4;
  float4 a = *(const float4*)(part + i);
#pragma unroll
  for (int s = 1; s < SK; ++s) {
    float4 b = *(const float4*)(part + (size_t)s * MN + i);
    a.x += b.x; a.y += b.y; a.z += b.z; a.w += b.w;
  }
  int col = (int)(i & (size_t)(N - 1));
  float4 bv = *(const float4*)(bias + col);
  float4 rv = *(const float4*)(res + i);
  float w = wsc[0];
  float4 o;
  o.x = rv.x * w + a.x + bv.x;
  o.y = rv.y * w + a.y + bv.y;
  o.z = rv.z * w + a.z + bv.z;
  o.w = rv.w * w + a.w + bv.w;
  *(float4*)(out + i) = o;
}

// ---------------- fused proj split-K reduce + residual + LayerNorm2 ----------------
__global__ __launch_bounds__(256) void reduce_ln(const float* __restrict__ part,
                                                 const float* __restrict__ bias,
                                                 const float* __restrict__ res,
                                                 const float* __restrict__ wsc,
                                                 const float* __restrict__ lng,
                                                 const float* __restrict__ lnb,
                                                 float* __restrict__ x2out,
                                                 bf16* __restrict__ lnout) {
  int row = blockIdx.x, tid = threadIdx.x;
  size_t i = ((size_t)row << 10) + tid * 4;
  float4 a = *(const float4*)(part + i);
  float4 b2 = *(const float4*)(part + 4194304 + i);
  float4 rv = *(const float4*)(res + i);
  float4 bv = *(const float4*)(bias + tid * 4);
  float w = wsc[0];
  float4 o;
  o.x = rv.x * w + a.x + b2.x + bv.x;
  o.y = rv.y * w + a.y + b2.y + bv.y;
  o.z = rv.z * w + a.z + b2.z + bv.z;
  o.w = rv.w * w + a.w + b2.w + bv.w;
  *(float4*)(x2out + i) = o;
  float s = o.x + o.y + o.z + o.w;
  float ss = o.x * o.x + o.y * o.y + o.z * o.z + o.w * o.w;
#pragma unroll
  for (int off = 32; off >= 1; off >>= 1) {
    s += __shfl_down(s, off);
    ss += __shfl_down(ss, off);
  }
  __shared__ float sh[8];
  int wid = tid >> 6;
  if ((tid & 63) == 0) { sh[wid] = s; sh[wid + 4] = ss; }
  __syncthreads();
  float ts = sh[0] + sh[1] + sh[2] + sh[3];
  float tss = sh[4] + sh[5] + sh[6] + sh[7];
  float mean = ts * (1.0f / 1024.0f);
  float var = tss * (1.0f / 1024.0f) - mean * mean;
  float inv = rsqrtf(var + 1e-5f);
  float4 gg = *(const float4*)(lng + tid * 4);
  float4 bb = *(const float4*)(lnb + tid * 4);
  bf16x4 ov;
  ov[0] = (bf16)((o.x - mean) * inv * gg.x + bb.x);
  ov[1] = (bf16)((o.y - mean) * inv * gg.y + bb.y);
  ov[2] = (bf16)((o.z - mean) * inv * gg.z + bb.z);
  ov[3] = (bf16)((o.w - mean) * inv * gg.w + bb.w);
  *(bf16x4*)(lnout + ((size_t)row << 10) + tid * 4) = ov;
}

// ---------------- V transpose from qkv: vT[bh][d][t] ----------------
__global__ __launch_bounds__(256) void split_v_t(const bf16* __restrict__ qkv,
                                                 bf16* __restrict__ vT) {
  int t0 = blockIdx.x * 32;
  int bh = blockIdx.y;
  int b = bh >> 4, h = bh & 15;
  __shared__ bf16 tile[32][72];
  int tid = threadIdx.x;
  int d = tid & 63, tl0 = tid >> 6;
#pragma unroll
  for (int p = 0; p < 8; ++p) {
    int tl = p * 4 + tl0;
    tile[tl][d] = qkv[((size_t)(b * 2048 + t0 + tl)) * 3072 + 2048 + h * 64 + d];
  }
  __syncthreads();
  int tl = tid & 31, dq = tid >> 5;
#pragma unroll
  for (int p = 0; p < 8; ++p) {
    int dd = p * 8 + dq;
    vT[((size_t)(bh * 64 + dd)) * 2048 + t0 + tl] = tile[tl][dd];
  }
}

// ---------------- flash attention fwd (LDS-staged K/V, dbuf, split-K=2, defer-max) ----------------
__global__ __launch_bounds__(256) void attn_fwd(const bf16* __restrict__ qkv,
                                                const bf16* __restrict__ vT,
                                                float* __restrict__ o_part,
                                                float* __restrict__ ml_part) {
  __shared__ __align__(16) bf16 Ks[2][4096];
  __shared__ __align__(16) bf16 Vs[2][4096];
  __shared__ bf16 P[4][16][72];
  int id = blockIdx.x;            // 0..2047
  int bh = id & 31;
  int seg = (id >> 5) & 1;
  int qi = ((id >> 6) + bh) & 31; // stagger causal depth
  int tid = threadIdx.x, wid = tid >> 6, lane = tid & 63;
  int g = lane >> 4, lr = lane & 15;
  int b = bh >> 4, h = bh & 15;
  int nk = qi + 1;
  int n0 = (nk + 1) >> 1;
  int kt0 = seg ? n0 : 0;
  int kt1 = seg ? nk : n0;
  int qrow = qi * 64 + wid * 16 + lr;
  const bf16* Qr = qkv + ((size_t)(b * 2048 + qrow)) * 3072 + h * 64;
  const float beta = 0.18033688f;  // 0.125 * log2(e): fold into Q
  bf16x8 qf[2];
  qf[0] = *(const bf16x8*)(Qr + g * 8);
  qf[1] = *(const bf16x8*)(Qr + 32 + g * 8);
#pragma unroll
  for (int kk = 0; kk < 2; ++kk)
#pragma unroll
    for (int e = 0; e < 8; ++e) qf[kk][e] = (bf16)((float)qf[kk][e] * beta);
  int r0 = tid >> 3, cs0 = ((tid & 7) ^ (r0 & 7)) << 3;
  int c1i = tid + 256;
  int r1 = c1i >> 3, cs1 = ((c1i & 7) ^ (r1 & 7)) << 3;
  const bf16* sK0 = qkv + ((size_t)(b * 2048 + r0)) * 3072 + 1024 + h * 64 + cs0;
  const bf16* sK1 = qkv + ((size_t)(b * 2048 + r1)) * 3072 + 1024 + h * 64 + cs1;
  const bf16* sV0 = vT + (size_t)bh * 131072 + (size_t)r0 * 2048 + cs0;
  const bf16* sV1 = vT + (size_t)bh * 131072 + (size_t)r1 * 2048 + cs1;
  bf16* dK0 = &Ks[0][0] + tid * 8;
  bf16* dK1 = &Ks[0][0] + 2048 + tid * 8;
  bf16* dV0 = &Vs[0][0] + tid * 8;
  bf16* dV1 = &Vs[0][0] + 2048 + tid * 8;
#define ATTN_STAGE(bufsel, ktv)                          \
  {                                                      \
    size_t kadv = (size_t)(ktv) * (64 * 3072);           \
    size_t vadv = (size_t)(ktv) * 64;                    \
    int bo = (bufsel) * 4096;                            \
    GLOAD_LDS16(sK0 + kadv, dK0 + bo);                   \
    GLOAD_LDS16(sK1 + kadv, dK1 + bo);                   \
    GLOAD_LDS16(sV0 + vadv, dV0 + bo);                   \
    GLOAD_LDS16(sV1 + vadv, dV1 + bo);                   \
  }
  f32x4 o[4];
#pragma unroll
  for (int n = 0; n < 4; ++n) o[n] = (f32x4){0.f, 0.f, 0.f, 0.f};
  float m = -3e38f, l = 0.f;
  if (kt0 < kt1) ATTN_STAGE(0, kt0);
  __syncthreads();
  int sw = lr & 7;
  int sb = (lane & 48) | (g << 2);
  for (int kt = kt0; kt < kt1; ++kt) {
    int cur = (kt - kt0) & 1;
    if (kt + 1 < kt1) ATTN_STAGE(cur ^ 1, kt + 1);
    const bf16* Kb = &Ks[cur][0];
    const bf16* Vb = &Vs[cur][0];
    f32x4 s[4];
#pragma unroll
    for (int n = 0; n < 4; ++n) s[n] = (f32x4){0.f, 0.f, 0.f, 0.f};
#pragma unroll
    for (int kk = 0; kk < 2; ++kk) {
#pragma unroll
      for (int n = 0; n < 4; ++n) {
        bf16x8 kf = *(const bf16x8*)(Kb + ((n * 16 + lr) << 6) + ((((kk << 2) + g) ^ sw) << 3));
        s[n] = MFMA(kf, qf[kk], s[n]);  // lane holds q-row lr, k-cols n*16+g*4+j (scaled)
      }
    }
    if (kt == qi) {  // diagonal tile only: causal mask (wave-uniform branch)
      int kc0 = kt * 64 + g * 4;
#pragma unroll
      for (int n = 0; n < 4; ++n)
#pragma unroll
        for (int j = 0; j < 4; ++j)
          if ((kc0 + n * 16 + j) > qrow) s[n][j] = -3e38f;
    }
    float mx = s[0][0];
#pragma unroll
    for (int n = 0; n < 4; ++n)
#pragma unroll
      for (int j = 0; j < 4; ++j) mx = fmaxf(mx, s[n][j]);
    mx = fmaxf(mx, __shfl_xor(mx, 16));
    mx = fmaxf(mx, __shfl_xor(mx, 32));
    // T13 defer-max: skip max-update + O-rescale when growth small (THR = 8*log2e)
    bool defer = __all(mx <= m + 11.5416f);
    float mn = m, al = 0.f;
    if (!defer) {
      mn = fmaxf(m, mx);
      al = exp2f(m - mn);
      m = mn;
    }
    float rs = 0.f;
    bf16x4 pw[4];
#pragma unroll
    for (int n = 0; n < 4; ++n)
#pragma unroll
      for (int j = 0; j < 4; ++j) {
        float p = exp2f(s[n][j] - mn);
        rs += p;
        pw[n][j] = (bf16)p;
      }
    rs += __shfl_xor(rs, 16);
    rs += __shfl_xor(rs, 32);
    if (defer) {
      l += rs;
    } else {
      l = l * al + rs;
      float alj[4];
#pragma unroll
      for (int j = 0; j < 4; ++j) alj[j] = __shfl(al, sb + j);
#pragma unroll
      for (int n = 0; n < 4; ++n)
#pragma unroll
        for (int j = 0; j < 4; ++j) o[n][j] *= alj[j];
    }
#pragma unroll
    for (int n = 0; n < 4; ++n) *(bf16x4*)&P[wid][lr][n * 16 + g * 4] = pw[n];
#pragma unroll
    for (int kk = 0; kk < 2; ++kk) {
      bf16x8 pf = *(const bf16x8*)&P[wid][lr][kk * 32 + g * 8];
#pragma unroll
      for (int n = 0; n < 4; ++n) {
        bf16x8 vf = *(const bf16x8*)(Vb + ((n * 16 + lr) << 6) + ((((kk << 2) + g) ^ sw) << 3));
        o[n] = MFMA(pf, vf, o[n]);
      }
    }
    __syncthreads();
  }
  float* ob = o_part + (size_t)id * 4096;
#pragma unroll
  for (int n = 0; n < 4; ++n)
#pragma unroll
    for (int j = 0; j < 4; ++j)
      ob[(size_t)(wid * 16 + g * 4 + j) * 64 + n * 16 + lr] = o[n][j];
  if (lane < 16) {
    ml_part[(size_t)id * 128 + (wid * 16 + lane) * 2] = m;
    ml_part[(size_t)id * 128 + (wid * 16 + lane) * 2 + 1] = l;
  }
#undef ATTN_STAGE
}

// ---------------- attention combine ----------------
__global__ __launch_bounds__(256) void attn_combine(const float* __restrict__ o_part,
                                                    const float* __restrict__ ml_part,
                                                    bf16* __restrict__ y) {
  int c = blockIdx.x;  // 0..1023: (bh, qi)
  int bh = c & 31, qi = c >> 5;
  int b = bh >> 4, h = bh & 15;
  int qraw = (qi - bh) & 31;
  size_t id0 = (size_t)bh + ((size_t)qraw << 6);
  size_t id1 = id0 + 32;
  int t = threadIdx.x;
  int r = t >> 2, cq = (t & 3) << 4;
  float m1 = ml_part[id0 * 128 + r * 2], l1 = ml_part[id0 * 128 + r * 2 + 1];
  float m2 = ml_part[id1 * 128 + r * 2], l2 = ml_part[id1 * 128 + r * 2 + 1];
  float mm = fmaxf(m1, m2);
  float w1 = exp2f(m1 - mm), w2 = exp2f(m2 - mm);
  float inv = 1.0f / (l1 * w1 + l2 * w2);
  const float* p1 = o_part + id0 * 4096 + r * 64 + cq;
  const float* p2 = o_part + id1 * 4096 + r * 64 + cq;
  bf16* yp = y + ((size_t)(b * 2048 + qi * 64 + r)) * 1024 + h * 64 + cq;
#pragma unroll
  for (int u = 0; u < 4; ++u) {
    float4 a = *(const float4*)(p1 + u * 4);
    float4 bq = *(const float4*)(p2 + u * 4);
    bf16x4 ov;
    ov[0] = (bf16)((a.x * w1 + bq.x * w2) * inv);
    ov[1] = (bf16)((a.y * w1 + bq.y * w2) * inv);
    ov[2] = (bf16)((a.z * w1 + bq.z * w2) * inv);
    ov[3] = (bf16)((a.w * w1 + bq.w * w2) * inv);
    *(bf16x4*)(yp + u * 4) = ov;
  }
}

// ---------------- launch ----------------
extern "C" void kernel_launch(void* const* d_in, const int* in_sizes, int n_in,
                              void* d_out, int out_size, void* d_ws, size_t ws_size,
                              hipStream_t stream) {
  const float* x = (const float*)d_in[0];
  const float* ln1_g = (const float*)d_in[1];
  const float* ln1_b = (const float*)d_in[2];
  const float* attn_w = (const float*)d_in[3];
  const float* attn_b = (const float*)d_in[4];
  const float* proj_w = (const float*)d_in[5];
  const float* proj_b = (const float*)d_in[6];
  const float* ln2_g = (const float*)d_in[7];
  const float* ln2_b = (const float*)d_in[8];
  const float* mlp_w1 = (const float*)d_in[9];
  const float* mlp_b1 = (const float*)d_in[10];
  const float* mlp_w2 = (const float*)d_in[11];
  const float* mlp_b2 = (const float*)d_in[12];
  const float* w_att = (const float*)d_in[13];
  const float* w_mlp = (const float*)d_in[14];
  float* out = (float*)d_out;

  unsigned char* base = nullptr;
  if (ws_size >= TOTAL_BYTES) {
    base = (unsigned char*)d_ws;
  } else {
    hipGetSymbolAddress((void**)&base, HIP_SYMBOL(g_buf));
  }
  bf16* bb = (bf16*)base;
  bf16* wt_attn = bb + E_WT_ATTN;
  bf16* wt_proj = bb + E_WT_PROJ;
  bf16* wt_mlp1 = bb + E_WT_MLP1;
  bf16* wt_mlp2 = bb + E_WT_MLP2;
  bf16* ln1o = bb + E_LN1;
  bf16* qkv = bb + E_QKV;
  bf16* vTb = bb + E_VT;
  bf16* yb = bb + E_Y;
  bf16* ln2o = bb + E_LN2;
  bf16* hb = bb + E_H;
  float* x2 = (float*)(base + BYTE_X2);
  float* o_part = (float*)(base + BYTE_OPART);
  float* ml_part = (float*)(base + BYTE_ML);
  float* gpart = (float*)(base + BYTE_GPART);

  transpose_all<<<12288, dim3(32, 8), 0, stream>>>(attn_w, proj_w, mlp_w1, mlp_w2,
                                                   wt_attn, wt_proj, wt_mlp1, wt_mlp2);

  ln_bf16<<<4096, 256, 0, stream>>>(x, ln1_g, ln1_b, ln1o);

  gemm256<0><<<dim3(12, 16, 1), 512, 0, stream>>>(ln1o, wt_attn, attn_b, qkv, nullptr,
                                                  4096, 3072, 1024, 1024);

  split_v_t<<<dim3(64, 32), 256, 0, stream>>>(qkv, vTb);

  attn_fwd<<<2048, 256, 0, stream>>>(qkv, vTb, o_part, ml_part);
  attn_combine<<<1024, 256, 0, stream>>>(o_part, ml_part, yb);

  gemm_bt3<<<dim3(8, 32, 2), 256, 0, stream>>>(yb, wt_proj, gpart, 4096, 1024, 1024, 512);
  reduce_ln<<<4096, 256, 0, stream>>>(gpart, proj_b, x, w_att, ln2_g, ln2_b, x2, ln2o);

  gemm256<1><<<dim3(16, 16, 1), 512, 0, stream>>>(ln2o, wt_mlp1, mlp_b1, hb, nullptr,
                                                  4096, 4096, 1024, 1024);

  gemm256<3><<<dim3(4, 16, 4), 512, 0, stream>>>(hb, wt_mlp2, nullptr, nullptr, gpart,
                                                 4096, 1024, 4096, 1024);
  reduce_add<4><<<4096, 256, 0, stream>>>(gpart, mlp_b2, x2, w_mlp, out, 4194304, 1024);
}

// Round 9
// 369.305 us; speedup vs baseline: 1.6714x; 1.0126x over previous
//
#include <hip/hip_runtime.h>
#include <math.h>

typedef __bf16 bf16;
typedef bf16 bf16x8 __attribute__((ext_vector_type(8)));
typedef bf16 bf16x4 __attribute__((ext_vector_type(4)));
typedef float f32x4 __attribute__((ext_vector_type(4)));

#define MFMA(a, b, c) __builtin_amdgcn_mfma_f32_16x16x32_bf16((a), (b), (c), 0, 0, 0)

#define GLOAD_LDS16(gp, lp)                                                        \
  __builtin_amdgcn_global_load_lds((const __attribute__((address_space(1))) void*)(gp), \
                                   (__attribute__((address_space(3))) void*)(lp), 16, 0, 0)

// ---------------- workspace layout ----------------
// bf16 element offsets
static const size_t E_WT_ATTN = 0;          // [3072][1024]
static const size_t E_WT_PROJ = 3145728;    // [1024][1024]
static const size_t E_WT_MLP1 = 4194304;    // [4096][1024]
static const size_t E_WT_MLP2 = 8388608;    // [1024][4096]
static const size_t E_LN1     = 12582912;   // [4096][1024]
static const size_t E_QKV     = 16777216;   // [4096][3072]
static const size_t E_VT      = 37748736;   // [B,H,64,T]
static const size_t E_Y       = 41943040;   // [4096][1024]
static const size_t E_LN2     = 46137344;   // [4096][1024]
static const size_t E_H       = 50331648;   // [4096][4096]
// byte offsets
static const size_t BYTE_X2    = 134217728; // float [4096][1024]
static const size_t BYTE_OPART = 150994944; // float [2048][64][64] attn partials
static const size_t BYTE_ML    = 184549376; // float [2048][64][2]
static const size_t BYTE_GPART = 185597952; // float [4][4096][1024] gemm split-K partials
static const size_t TOTAL_BYTES = 252706816;

__device__ __align__(4096) unsigned char g_buf[TOTAL_BYTES];

// ---------------- merged transpose+cast for all 4 weights ----------------
// f32 [K][N] -> bf16 [N][K]
__global__ __launch_bounds__(256) void transpose_all(const float* __restrict__ aw,
                                                     const float* __restrict__ pw,
                                                     const float* __restrict__ m1,
                                                     const float* __restrict__ m2,
                                                     bf16* __restrict__ o_a,
                                                     bf16* __restrict__ o_p,
                                                     bf16* __restrict__ o_m1,
                                                     bf16* __restrict__ o_m2) {
  __shared__ float tile[32][33];
  int bid = blockIdx.x;
  const float* in;
  bf16* out;
  int K, N, tix;
  if (bid < 3072) { in = aw; out = o_a; K = 1024; N = 3072; tix = bid; }
  else if (bid < 4096) { in = pw; out = o_p; K = 1024; N = 1024; tix = bid - 3072; }
  else if (bid < 8192) { in = m1; out = o_m1; K = 1024; N = 4096; tix = bid - 4096; }
  else { in = m2; out = o_m2; K = 4096; N = 1024; tix = bid - 8192; }
  int ntx = N >> 5;
  int bx = tix % ntx, by = tix / ntx;
  int tx = threadIdx.x, ty = threadIdx.y;
#pragma unroll
  for (int i = ty; i < 32; i += 8)
    tile[i][tx] = in[(size_t)(by * 32 + i) * N + bx * 32 + tx];
  __syncthreads();
#pragma unroll
  for (int i = ty; i < 32; i += 8)
    out[(size_t)(bx * 32 + i) * K + by * 32 + tx] = (bf16)tile[tx][i];
}

// ---------------- LayerNorm f32 row(1024) -> bf16 ----------------
__global__ __launch_bounds__(256) void ln_bf16(const float* __restrict__ x,
                                               const float* __restrict__ g,
                                               const float* __restrict__ b,
                                               bf16* __restrict__ out) {
  int row = blockIdx.x, tid = threadIdx.x;
  const float* xr = x + ((size_t)row << 10);
  float4 v = *(const float4*)(xr + tid * 4);
  float s = v.x + v.y + v.z + v.w;
  float ss = v.x * v.x + v.y * v.y + v.z * v.z + v.w * v.w;
#pragma unroll
  for (int off = 32; off >= 1; off >>= 1) {
    s += __shfl_down(s, off);
    ss += __shfl_down(ss, off);
  }
  __shared__ float sh[8];
  int wid = tid >> 6;
  if ((tid & 63) == 0) { sh[wid] = s; sh[wid + 4] = ss; }
  __syncthreads();
  float ts = sh[0] + sh[1] + sh[2] + sh[3];
  float tss = sh[4] + sh[5] + sh[6] + sh[7];
  float mean = ts * (1.0f / 1024.0f);
  float var = tss * (1.0f / 1024.0f) - mean * mean;
  float inv = rsqrtf(var + 1e-5f);
  float4 gg = *(const float4*)(g + tid * 4);
  float4 bb = *(const float4*)(b + tid * 4);
  bf16x4 o;
  o[0] = (bf16)((v.x - mean) * inv * gg.x + bb.x);
  o[1] = (bf16)((v.y - mean) * inv * gg.y + bb.y);
  o[2] = (bf16)((v.z - mean) * inv * gg.z + bb.z);
  o[3] = (bf16)((v.w - mean) * inv * gg.w + bb.w);
  *(bf16x4*)(out + ((size_t)row << 10) + tid * 4) = o;
}

// ---------------- 256x256 GEMM, BK=64, 8 waves, dbuf LDS, swizzled ----------------
// T4 counted-vmcnt pipeline + T5 setprio. C[M][N] = A[M][K] @ Bt[N][K]^T.
// EPI 0: bf16(acc+bias); 1: bf16(gelu(acc+bias)); 3: outf[z*M*N+idx] = acc
template <int EPI>
__global__ __launch_bounds__(512, 2) void gemm256(const bf16* __restrict__ A,
                                                  const bf16* __restrict__ Bt,
                                                  const float* __restrict__ bias,
                                                  bf16* __restrict__ outb,
                                                  float* __restrict__ outf,
                                                  int M, int N, int K, int Kseg) {
  __shared__ __align__(16) bf16 As[2][16384];  // [buf][256*64]
  __shared__ __align__(16) bf16 Bs[2][16384];
  int tid = threadIdx.x;
  // XCD-contiguous tile remap (nwg % 8 == 0 for all our grids)
  int nwg = gridDim.x * gridDim.y;
  int bid = blockIdx.y * gridDim.x + blockIdx.x;
  int id2 = ((nwg & 7) == 0) ? ((bid & 7) * (nwg >> 3) + (bid >> 3)) : bid;
  int bx = id2 % gridDim.x, by = id2 / gridDim.x;
  int lane = tid & 63, wid = tid >> 6;
  int wr = wid >> 2, wc = wid & 3;  // 2 x 4 waves
  int g = lane >> 4, lr = lane & 15;
  f32x4 acc[8][4];
#pragma unroll
  for (int m = 0; m < 8; ++m)
#pragma unroll
    for (int n = 0; n < 4; ++n) acc[m][n] = (f32x4){0.f, 0.f, 0.f, 0.f};
  const bf16* Ab = A + (size_t)by * 256 * K;
  const bf16* Bb = Bt + (size_t)bx * 256 * K;
  int rbase = tid >> 3;
  int srccol = (((tid & 7) ^ (rbase & 7)) << 3);
  const bf16* Asrc = Ab + (size_t)rbase * K + srccol;
  const bf16* Bsrc = Bb + (size_t)rbase * K + srccol;
#define G256_STAGE(buf, k0)                                                \
  {                                                                        \
    _Pragma("unroll") for (int q = 0; q < 4; ++q) {                        \
      GLOAD_LDS16(Asrc + (size_t)(q * 64) * K + (k0), &As[buf][tid * 8 + q * 4096]); \
      GLOAD_LDS16(Bsrc + (size_t)(q * 64) * K + (k0), &Bs[buf][tid * 8 + q * 4096]); \
    }                                                                      \
  }
  int kbeg = blockIdx.z * Kseg;
  int NT = Kseg >> 6;
  // prologue: stage tiles 0 and 1; wait only for tile 0 (tile 1's 8 loads stay in flight)
  G256_STAGE(0, kbeg);
  if (NT > 1) {
    G256_STAGE(1, kbeg + 64);
    asm volatile("s_waitcnt vmcnt(8)" ::: "memory");
  } else {
    asm volatile("s_waitcnt vmcnt(0)" ::: "memory");
  }
  __builtin_amdgcn_sched_barrier(0);
  __builtin_amdgcn_s_barrier();
  int c = 0;
  for (int t = 0; t < NT; ++t) {
    bf16x8 a0[8], b0[4], a1[8], b1[4];
#pragma unroll
    for (int m = 0; m < 8; ++m) {
      int row = wr * 128 + m * 16 + lr;
      a0[m] = *(const bf16x8*)&As[c][row * 64 + ((g ^ (row & 7)) << 3)];
      a1[m] = *(const bf16x8*)&As[c][row * 64 + (((4 + g) ^ (row & 7)) << 3)];
    }
#pragma unroll
    for (int n = 0; n < 4; ++n) {
      int row = wc * 64 + n * 16 + lr;
      b0[n] = *(const bf16x8*)&Bs[c][row * 64 + ((g ^ (row & 7)) << 3)];
      b1[n] = *(const bf16x8*)&Bs[c][row * 64 + (((4 + g) ^ (row & 7)) << 3)];
    }
    // kk=0 MFMA cluster
    __builtin_amdgcn_s_setprio(1);
#pragma unroll
    for (int m = 0; m < 8; ++m)
#pragma unroll
      for (int n = 0; n < 4; ++n) acc[m][n] = MFMA(a0[m], b0[n], acc[m][n]);
    __builtin_amdgcn_s_setprio(0);
    // all ds_reads of buf c complete before anyone overwrites it
    asm volatile("s_waitcnt lgkmcnt(0)" ::: "memory");
    __builtin_amdgcn_sched_barrier(0);
    __builtin_amdgcn_s_barrier();
    if (t + 2 < NT) G256_STAGE(c, kbeg + (t + 2) * 64);  // overwrite c with tile t+2
    // kk=1 MFMA cluster (register operands; overlaps the staging loads)
    __builtin_amdgcn_s_setprio(1);
#pragma unroll
    for (int m = 0; m < 8; ++m)
#pragma unroll
      for (int n = 0; n < 4; ++n) acc[m][n] = MFMA(a1[m], b1[n], acc[m][n]);
    __builtin_amdgcn_s_setprio(0);
    // counted wait: retire tile t+1's 8 loads, keep tile t+2's 8 in flight
    if (t + 2 < NT) {
      asm volatile("s_waitcnt vmcnt(8)" ::: "memory");
    } else if (t + 1 < NT) {
      asm volatile("s_waitcnt vmcnt(0)" ::: "memory");
    }
    __builtin_amdgcn_sched_barrier(0);
    __builtin_amdgcn_s_barrier();  // tile t+1 fully resident in buf c^1
    c ^= 1;
  }
#undef G256_STAGE
  if (EPI == 3) {
    float* po = outf + (size_t)blockIdx.z * M * N;
#pragma unroll
    for (int m = 0; m < 8; ++m) {
#pragma unroll
      for (int n = 0; n < 4; ++n) {
        int rg0 = by * 256 + wr * 128 + m * 16 + g * 4;
        int cg = bx * 256 + wc * 64 + n * 16 + lr;
#pragma unroll
        for (int j = 0; j < 4; ++j) po[(size_t)(rg0 + j) * N + cg] = acc[m][n][j];
      }
    }
  } else {
#pragma unroll
    for (int m = 0; m < 8; ++m) {
#pragma unroll
      for (int n = 0; n < 4; ++n) {
        int rg0 = by * 256 + wr * 128 + m * 16 + g * 4;
        int cg = bx * 256 + wc * 64 + n * 16 + lr;
        float bv = bias[cg];
#pragma unroll
        for (int j = 0; j < 4; ++j) {
          float v = acc[m][n][j] + bv;
          size_t idx = (size_t)(rg0 + j) * N + cg;
          if (EPI == 0)
            outb[idx] = (bf16)v;
          else {
            // exact-gelu via tanh form (branch-free, |err|<0.003)
            float u = 0.7978845608f * (v + 0.044715f * v * v * v);
            float e = exp2f(u * 2.885390082f);  // exp(2u)
            float th = 1.0f - 2.0f / (e + 1.0f);
            outb[idx] = (bf16)(0.5f * v * (1.0f + th));
          }
        }
      }
    }
  }
}

// ---------------- 128x128 GEMM (split-K partial only) ----------------
__global__ __launch_bounds__(256) void gemm_bt3(const bf16* __restrict__ A,
                                                const bf16* __restrict__ Bt,
                                                float* __restrict__ outf,
                                                int M, int N, int K, int Kseg) {
  __shared__ __align__(16) bf16 As[128 * 32];
  __shared__ __align__(16) bf16 Bs[128 * 32];
  int bx = blockIdx.x, by = blockIdx.y;
  int tid = threadIdx.x;
  int lane = tid & 63, wid = tid >> 6;
  int wr = wid >> 1, wc = wid & 1;
  int g = lane >> 4, lr = lane & 15;
  f32x4 acc[4][4];
#pragma unroll
  for (int m = 0; m < 4; ++m)
#pragma unroll
    for (int n = 0; n < 4; ++n) acc[m][n] = (f32x4){0.f, 0.f, 0.f, 0.f};
  const bf16* Ab = A + (size_t)by * 128 * K;
  const bf16* Bb = Bt + (size_t)bx * 128 * K;
  int srow = tid >> 2;
  int sk8 = (tid & 3) * 8;
  const bf16* Ap0 = Ab + (size_t)srow * K + sk8;
  const bf16* Ap1 = Ab + (size_t)(srow + 64) * K + sk8;
  const bf16* Bp0 = Bb + (size_t)srow * K + sk8;
  const bf16* Bp1 = Bb + (size_t)(srow + 64) * K + sk8;
  bf16* lA0 = As + tid * 8;
  bf16* lA1 = As + 2048 + tid * 8;
  bf16* lB0 = Bs + tid * 8;
  bf16* lB1 = Bs + 2048 + tid * 8;
  int kbeg = blockIdx.z * Kseg;
  int kend = kbeg + Kseg;
  for (int k0 = kbeg; k0 < kend; k0 += 32) {
    GLOAD_LDS16(Ap0 + k0, lA0);
    GLOAD_LDS16(Ap1 + k0, lA1);
    GLOAD_LDS16(Bp0 + k0, lB0);
    GLOAD_LDS16(Bp1 + k0, lB1);
    __syncthreads();
    bf16x8 af[4], bfv[4];
#pragma unroll
    for (int m = 0; m < 4; ++m) af[m] = *(const bf16x8*)(As + (wr * 64 + m * 16 + lr) * 32 + g * 8);
#pragma unroll
    for (int n = 0; n < 4; ++n) bfv[n] = *(const bf16x8*)(Bs + (wc * 64 + n * 16 + lr) * 32 + g * 8);
#pragma unroll
    for (int m = 0; m < 4; ++m)
#pragma unroll
      for (int n = 0; n < 4; ++n) acc[m][n] = MFMA(af[m], bfv[n], acc[m][n]);
    __syncthreads();
  }
  float* po = outf + (size_t)blockIdx.z * M * N;
#pragma unroll
  for (int m = 0; m < 4; ++m) {
#pragma unroll
    for (int n = 0; n < 4; ++n) {
      int rg0 = by * 128 + wr * 64 + m * 16 + g * 4;
      int cg = bx * 128 + wc * 64 + n * 16 + lr;
#pragma unroll
      for (int j = 0; j < 4; ++j) po[(size_t)(rg0 + j) * N + cg] = acc[m][n][j];
    }
  }
}

// ---------------- split-K reduce: out = res*w + sum(parts) + bias ----------------
template <int SK>
__global__ __launch_bounds__(256) void reduce_add(const float* __restrict__ part,
                                                  const float* __restrict__ bias,
                                                  const float* __restrict__ res,
                                                  const float* __restrict__ wsc,
                                                  float* __restrict__ out, int MN, int N) {
  size_t i = ((size_t)blockIdx.x * 256 + threadIdx.x) * 4;
  float4 a = *(const float4*)(part + i);
#pragma unroll
  for (int s = 1; s < SK; ++s) {
    float4 b = *(const float4*)(part + (size_t)s * MN + i);
    a.x += b.x; a.y += b.y; a.z += b.z; a.w += b.w;
  }
  int col = (int)(i & (size_t)(N - 1));
  float4 bv = *(const float4*)(bias + col);
  float4 rv = *(const float4*)(res + i);
  float w = wsc[0];
  float4 o;
  o.x = rv.x * w + a.x + bv.x;
  o.y = rv.y * w + a.y + bv.y;
  o.z = rv.z * w + a.z + bv.z;
  o.w = rv.w * w + a.w + bv.w;
  *(float4*)(out + i) = o;
}

// ---------------- fused proj split-K reduce + residual + LayerNorm2 ----------------
__global__ __launch_bounds__(256) void reduce_ln(const float* __restrict__ part,
                                                 const float* __restrict__ bias,
                                                 const float* __restrict__ res,
                                                 const float* __restrict__ wsc,
                                                 const float* __restrict__ lng,
                                                 const float* __restrict__ lnb,
                                                 float* __restrict__ x2out,
                                                 bf16* __restrict__ lnout) {
  int row = blockIdx.x, tid = threadIdx.x;
  size_t i = ((size_t)row << 10) + tid * 4;
  float4 a = *(const float4*)(part + i);
  float4 b2 = *(const float4*)(part + 4194304 + i);
  float4 rv = *(const float4*)(res + i);
  float4 bv = *(const float4*)(bias + tid * 4);
  float w = wsc[0];
  float4 o;
  o.x = rv.x * w + a.x + b2.x + bv.x;
  o.y = rv.y * w + a.y + b2.y + bv.y;
  o.z = rv.z * w + a.z + b2.z + bv.z;
  o.w = rv.w * w + a.w + b2.w + bv.w;
  *(float4*)(x2out + i) = o;
  float s = o.x + o.y + o.z + o.w;
  float ss = o.x * o.x + o.y * o.y + o.z * o.z + o.w * o.w;
#pragma unroll
  for (int off = 32; off >= 1; off >>= 1) {
    s += __shfl_down(s, off);
    ss += __shfl_down(ss, off);
  }
  __shared__ float sh[8];
  int wid = tid >> 6;
  if ((tid & 63) == 0) { sh[wid] = s; sh[wid + 4] = ss; }
  __syncthreads();
  float ts = sh[0] + sh[1] + sh[2] + sh[3];
  float tss = sh[4] + sh[5] + sh[6] + sh[7];
  float mean = ts * (1.0f / 1024.0f);
  float var = tss * (1.0f / 1024.0f) - mean * mean;
  float inv = rsqrtf(var + 1e-5f);
  float4 gg = *(const float4*)(lng + tid * 4);
  float4 bb = *(const float4*)(lnb + tid * 4);
  bf16x4 ov;
  ov[0] = (bf16)((o.x - mean) * inv * gg.x + bb.x);
  ov[1] = (bf16)((o.y - mean) * inv * gg.y + bb.y);
  ov[2] = (bf16)((o.z - mean) * inv * gg.z + bb.z);
  ov[3] = (bf16)((o.w - mean) * inv * gg.w + bb.w);
  *(bf16x4*)(lnout + ((size_t)row << 10) + tid * 4) = ov;
}

// ---------------- V transpose from qkv: vT[bh][d][t] ----------------
__global__ __launch_bounds__(256) void split_v_t(const bf16* __restrict__ qkv,
                                                 bf16* __restrict__ vT) {
  int t0 = blockIdx.x * 32;
  int bh = blockIdx.y;
  int b = bh >> 4, h = bh & 15;
  __shared__ bf16 tile[32][72];
  int tid = threadIdx.x;
  int d = tid & 63, tl0 = tid >> 6;
#pragma unroll
  for (int p = 0; p < 8; ++p) {
    int tl = p * 4 + tl0;
    tile[tl][d] = qkv[((size_t)(b * 2048 + t0 + tl)) * 3072 + 2048 + h * 64 + d];
  }
  __syncthreads();
  int tl = tid & 31, dq = tid >> 5;
#pragma unroll
  for (int p = 0; p < 8; ++p) {
    int dd = p * 8 + dq;
    vT[((size_t)(bh * 64 + dd)) * 2048 + t0 + tl] = tile[tl][dd];
  }
}

// ---------------- flash attention fwd: paired K-tiles, counted vmcnt, defer-max ----------------
__global__ __launch_bounds__(256) void attn_fwd(const bf16* __restrict__ qkv,
                                                const bf16* __restrict__ vT,
                                                float* __restrict__ o_part,
                                                float* __restrict__ ml_part) {
  __shared__ __align__(16) bf16 Ks[2][4096];
  __shared__ __align__(16) bf16 Vs[2][4096];
  __shared__ bf16 P[4][16][136];
  int id = blockIdx.x;            // 0..2047
  int bh = id & 31;
  int seg = (id >> 5) & 1;
  int qi = ((id >> 6) + bh) & 31; // stagger causal depth
  int tid = threadIdx.x, wid = tid >> 6, lane = tid & 63;
  int g = lane >> 4, lr = lane & 15;
  int b = bh >> 4, h = bh & 15;
  int nk = qi + 1;
  int n0 = (nk + 1) >> 1;
  int kt0 = seg ? n0 : 0;
  int kt1 = seg ? nk : n0;
  int nt = kt1 - kt0;
  int qrow = qi * 64 + wid * 16 + lr;
  const bf16* Qr = qkv + ((size_t)(b * 2048 + qrow)) * 3072 + h * 64;
  const float beta = 0.18033688f;  // 0.125 * log2(e): fold into Q
  bf16x8 qf[2];
  qf[0] = *(const bf16x8*)(Qr + g * 8);
  qf[1] = *(const bf16x8*)(Qr + 32 + g * 8);
#pragma unroll
  for (int kk = 0; kk < 2; ++kk)
#pragma unroll
    for (int e = 0; e < 8; ++e) qf[kk][e] = (bf16)((float)qf[kk][e] * beta);
  int r0 = tid >> 3, cs0 = ((tid & 7) ^ (r0 & 7)) << 3;
  int c1i = tid + 256;
  int r1 = c1i >> 3, cs1 = ((c1i & 7) ^ (r1 & 7)) << 3;
  const bf16* sK0 = qkv + ((size_t)(b * 2048 + r0)) * 3072 + 1024 + h * 64 + cs0;
  const bf16* sK1 = qkv + ((size_t)(b * 2048 + r1)) * 3072 + 1024 + h * 64 + cs1;
  const bf16* sV0 = vT + (size_t)bh * 131072 + (size_t)r0 * 2048 + cs0;
  const bf16* sV1 = vT + (size_t)bh * 131072 + (size_t)r1 * 2048 + cs1;
  bf16* dK0 = &Ks[0][0] + tid * 8;
  bf16* dK1 = &Ks[0][0] + 2048 + tid * 8;
  bf16* dV0 = &Vs[0][0] + tid * 8;
  bf16* dV1 = &Vs[0][0] + 2048 + tid * 8;
  // over-staged tiles (ktv >= kt1) read in-bounds garbage inside g_buf; never consumed.
#define STAGE_K(bufsel, ktv)                              \
  {                                                       \
    size_t kadv = (size_t)(ktv) * (64 * 3072);            \
    int bo = (bufsel) * 4096;                             \
    GLOAD_LDS16(sK0 + kadv, dK0 + bo);                    \
    GLOAD_LDS16(sK1 + kadv, dK1 + bo);                    \
  }
#define STAGE_V(bufsel, ktv)                              \
  {                                                       \
    size_t vadv = (size_t)(ktv) * 64;                     \
    int bo = (bufsel) * 4096;                             \
    GLOAD_LDS16(sV0 + vadv, dV0 + bo);                    \
    GLOAD_LDS16(sV1 + vadv, dV1 + bo);                    \
  }
  f32x4 o[4];
#pragma unroll
  for (int n = 0; n < 4; ++n) o[n] = (f32x4){0.f, 0.f, 0.f, 0.f};
  float m = -3e38f, l = 0.f;
  int sw = lr & 7;
  int sb = (lane & 48) | (g << 2);
  if (nt > 0) {
    STAGE_K(0, kt0);
    STAGE_K(1, kt0 + 1);
    STAGE_V(0, kt0);
    STAGE_V(1, kt0 + 1);
  }
  int kt = kt0;
  // -------- pair loop: tiles (kt, kt+1), one combined softmax over 128 cols --------
  for (; kt + 2 <= kt1; kt += 2) {
    asm volatile("s_waitcnt vmcnt(4)" ::: "memory");  // K pair resident
    __builtin_amdgcn_sched_barrier(0);
    __builtin_amdgcn_s_barrier();
    f32x4 s0[4], s1[4];
#pragma unroll
    for (int n = 0; n < 4; ++n) { s0[n] = (f32x4){0.f,0.f,0.f,0.f}; s1[n] = (f32x4){0.f,0.f,0.f,0.f}; }
    __builtin_amdgcn_s_setprio(1);
#pragma unroll
    for (int kk = 0; kk < 2; ++kk) {
#pragma unroll
      for (int n = 0; n < 4; ++n) {
        int off = ((n * 16 + lr) << 6) + ((((kk << 2) + g) ^ sw) << 3);
        bf16x8 kf0 = *(const bf16x8*)(&Ks[0][0] + off);
        s0[n] = MFMA(kf0, qf[kk], s0[n]);
        bf16x8 kf1 = *(const bf16x8*)(&Ks[1][0] + off);
        s1[n] = MFMA(kf1, qf[kk], s1[n]);
      }
    }
    __builtin_amdgcn_s_setprio(0);
    asm volatile("s_waitcnt lgkmcnt(0)" ::: "memory");  // all K reads done
    __builtin_amdgcn_sched_barrier(0);
    __builtin_amdgcn_s_barrier();
    STAGE_K(0, kt + 2);
    STAGE_K(1, kt + 3);
    if (kt + 1 == qi) {  // diagonal can only be the second tile of the pair
      int kc0 = (kt + 1) * 64 + g * 4;
#pragma unroll
      for (int n = 0; n < 4; ++n)
#pragma unroll
        for (int j = 0; j < 4; ++j)
          if ((kc0 + n * 16 + j) > qrow) s1[n][j] = -3e38f;
    }
    // combined online softmax over both tiles (32 values/lane)
    float mx = s0[0][0];
#pragma unroll
    for (int n = 0; n < 4; ++n)
#pragma unroll
      for (int j = 0; j < 4; ++j) { mx = fmaxf(mx, s0[n][j]); mx = fmaxf(mx, s1[n][j]); }
    mx = fmaxf(mx, __shfl_xor(mx, 16));
    mx = fmaxf(mx, __shfl_xor(mx, 32));
    bool defer = __all(mx <= m + 11.5416f);
    float mn = m, al = 0.f;
    if (!defer) {
      mn = fmaxf(m, mx);
      al = exp2f(m - mn);
      m = mn;
    }
    float rs = 0.f;
    bf16x4 pw0[4], pw1[4];
#pragma unroll
    for (int n = 0; n < 4; ++n)
#pragma unroll
      for (int j = 0; j < 4; ++j) {
        float p0 = exp2f(s0[n][j] - mn);
        float p1 = exp2f(s1[n][j] - mn);
        rs += p0 + p1;
        pw0[n][j] = (bf16)p0;
        pw1[n][j] = (bf16)p1;
      }
    rs += __shfl_xor(rs, 16);
    rs += __shfl_xor(rs, 32);
    if (defer) {
      l += rs;
    } else {
      l = l * al + rs;
      float alj[4];
#pragma unroll
      for (int j = 0; j < 4; ++j) alj[j] = __shfl(al, sb + j);
#pragma unroll
      for (int n = 0; n < 4; ++n)
#pragma unroll
        for (int j = 0; j < 4; ++j) o[n][j] *= alj[j];
    }
#pragma unroll
    for (int n = 0; n < 4; ++n) {
      *(bf16x4*)&P[wid][lr][n * 16 + g * 4] = pw0[n];
      *(bf16x4*)&P[wid][lr][64 + n * 16 + g * 4] = pw1[n];
    }
    asm volatile("s_waitcnt vmcnt(4)" ::: "memory");  // V pair resident
    __builtin_amdgcn_sched_barrier(0);
    __builtin_amdgcn_s_barrier();
    __builtin_amdgcn_s_setprio(1);
#pragma unroll
    for (int kk = 0; kk < 2; ++kk) {
      bf16x8 pf0 = *(const bf16x8*)&P[wid][lr][kk * 32 + g * 8];
      bf16x8 pf1 = *(const bf16x8*)&P[wid][lr][64 + kk * 32 + g * 8];
#pragma unroll
      for (int n = 0; n < 4; ++n) {
        int off = ((n * 16 + lr) << 6) + ((((kk << 2) + g) ^ sw) << 3);
        bf16x8 vf0 = *(const bf16x8*)(&Vs[0][0] + off);
        o[n] = MFMA(pf0, vf0, o[n]);
        bf16x8 vf1 = *(const bf16x8*)(&Vs[1][0] + off);
        o[n] = MFMA(pf1, vf1, o[n]);
      }
    }
    __builtin_amdgcn_s_setprio(0);
    asm volatile("s_waitcnt lgkmcnt(0)" ::: "memory");  // all V reads done
    __builtin_amdgcn_sched_barrier(0);
    __builtin_amdgcn_s_barrier();
    STAGE_V(0, kt + 2);
    STAGE_V(1, kt + 3);
  }
  // -------- tail: single tile --------
  if (kt < kt1) {
    int lb = (kt - kt0) & 1;
    asm volatile("s_waitcnt vmcnt(4)" ::: "memory");  // K(tail) resident
    __builtin_amdgcn_sched_barrier(0);
    __builtin_amdgcn_s_barrier();
    f32x4 s0[4];
#pragma unroll
    for (int n = 0; n < 4; ++n) s0[n] = (f32x4){0.f,0.f,0.f,0.f};
    __builtin_amdgcn_s_setprio(1);
#pragma unroll
    for (int kk = 0; kk < 2; ++kk) {
#pragma unroll
      for (int n = 0; n < 4; ++n) {
        int off = ((n * 16 + lr) << 6) + ((((kk << 2) + g) ^ sw) << 3);
        bf16x8 kf = *(const bf16x8*)(&Ks[lb][0] + off);
        s0[n] = MFMA(kf, qf[kk], s0[n]);
      }
    }
    __builtin_amdgcn_s_setprio(0);
    if (kt == qi) {
      int kc0 = kt * 64 + g * 4;
#pragma unroll
      for (int n = 0; n < 4; ++n)
#pragma unroll
        for (int j = 0; j < 4; ++j)
          if ((kc0 + n * 16 + j) > qrow) s0[n][j] = -3e38f;
    }
    float mx = s0[0][0];
#pragma unroll
    for (int n = 0; n < 4; ++n)
#pragma unroll
      for (int j = 0; j < 4; ++j) mx = fmaxf(mx, s0[n][j]);
    mx = fmaxf(mx, __shfl_xor(mx, 16));
    mx = fmaxf(mx, __shfl_xor(mx, 32));
    bool defer = __all(mx <= m + 11.5416f);
    float mn = m, al = 0.f;
    if (!defer) {
      mn = fmaxf(m, mx);
      al = exp2f(m - mn);
      m = mn;
    }
    float rs = 0.f;
    bf16x4 pw0[4];
#pragma unroll
    for (int n = 0; n < 4; ++n)
#pragma unroll
      for (int j = 0; j < 4; ++j) {
        float p = exp2f(s0[n][j] - mn);
        rs += p;
        pw0[n][j] = (bf16)p;
      }
    rs += __shfl_xor(rs, 16);
    rs += __shfl_xor(rs, 32);
    if (defer) {
      l += rs;
    } else {
      l = l * al + rs;
      float alj[4];
#pragma unroll
      for (int j = 0; j < 4; ++j) alj[j] = __shfl(al, sb + j);
#pragma unroll
      for (int n = 0; n < 4; ++n)
#pragma unroll
        for (int j = 0; j < 4; ++j) o[n][j] *= alj[j];
    }
#pragma unroll
    for (int n = 0; n < 4; ++n) *(bf16x4*)&P[wid][lr][n * 16 + g * 4] = pw0[n];
    asm volatile("s_waitcnt vmcnt(0)" ::: "memory");  // V(tail) resident
    __builtin_amdgcn_sched_barrier(0);
    __builtin_amdgcn_s_barrier();
    __builtin_amdgcn_s_setprio(1);
#pragma unroll
    for (int kk = 0; kk < 2; ++kk) {
      bf16x8 pf = *(const bf16x8*)&P[wid][lr][kk * 32 + g * 8];
#pragma unroll
      for (int n = 0; n < 4; ++n) {
        int off = ((n * 16 + lr) << 6) + ((((kk << 2) + g) ^ sw) << 3);
        bf16x8 vf = *(const bf16x8*)(&Vs[lb][0] + off);
        o[n] = MFMA(pf, vf, o[n]);
      }
    }
    __builtin_amdgcn_s_setprio(0);
  }
  float* ob = o_part + (size_t)id * 4096;
#pragma unroll
  for (int n = 0; n < 4; ++n)
#pragma unroll
    for (int j = 0; j < 4; ++j)
      ob[(size_t)(wid * 16 + g * 4 + j) * 64 + n * 16 + lr] = o[n][j];
  if (lane < 16) {
    ml_part[(size_t)id * 128 + (wid * 16 + lane) * 2] = m;
    ml_part[(size_t)id * 128 + (wid * 16 + lane) * 2 + 1] = l;
  }
#undef STAGE_K
#undef STAGE_V
}

// ---------------- attention combine ----------------
__global__ __launch_bounds__(256) void attn_combine(const float* __restrict__ o_part,
                                                    const float* __restrict__ ml_part,
                                                    bf16* __restrict__ y) {
  int c = blockIdx.x;  // 0..1023: (bh, qi)
  int bh = c & 31, qi = c >> 5;
  int b = bh >> 4, h = bh & 15;
  int qraw = (qi - bh) & 31;
  size_t id0 = (size_t)bh + ((size_t)qraw << 6);
  size_t id1 = id0 + 32;
  int t = threadIdx.x;
  int r = t >> 2, cq = (t & 3) << 4;
  float m1 = ml_part[id0 * 128 + r * 2], l1 = ml_part[id0 * 128 + r * 2 + 1];
  float m2 = ml_part[id1 * 128 + r * 2], l2 = ml_part[id1 * 128 + r * 2 + 1];
  float mm = fmaxf(m1, m2);
  float w1 = exp2f(m1 - mm), w2 = exp2f(m2 - mm);
  float inv = 1.0f / (l1 * w1 + l2 * w2);
  const float* p1 = o_part + id0 * 4096 + r * 64 + cq;
  const float* p2 = o_part + id1 * 4096 + r * 64 + cq;
  bf16* yp = y + ((size_t)(b * 2048 + qi * 64 + r)) * 1024 + h * 64 + cq;
#pragma unroll
  for (int u = 0; u < 4; ++u) {
    float4 a = *(const float4*)(p1 + u * 4);
    float4 bq = *(const float4*)(p2 + u * 4);
    bf16x4 ov;
    ov[0] = (bf16)((a.x * w1 + bq.x * w2) * inv);
    ov[1] = (bf16)((a.y * w1 + bq.y * w2) * inv);
    ov[2] = (bf16)((a.z * w1 + bq.z * w2) * inv);
    ov[3] = (bf16)((a.w * w1 + bq.w * w2) * inv);
    *(bf16x4*)(yp + u * 4) = ov;
  }
}

// ---------------- launch ----------------
extern "C" void kernel_launch(void* const* d_in, const int* in_sizes, int n_in,
                              void* d_out, int out_size, void* d_ws, size_t ws_size,
                              hipStream_t stream) {
  const float* x = (const float*)d_in[0];
  const float* ln1_g = (const float*)d_in[1];
  const float* ln1_b = (const float*)d_in[2];
  const float* attn_w = (const float*)d_in[3];
  const float* attn_b = (const float*)d_in[4];
  const float* proj_w = (const float*)d_in[5];
  const float* proj_b = (const float*)d_in[6];
  const float* ln2_g = (const float*)d_in[7];
  const float* ln2_b = (const float*)d_in[8];
  const float* mlp_w1 = (const float*)d_in[9];
  const float* mlp_b1 = (const float*)d_in[10];
  const float* mlp_w2 = (const float*)d_in[11];
  const float* mlp_b2 = (const float*)d_in[12];
  const float* w_att = (const float*)d_in[13];
  const float* w_mlp = (const float*)d_in[14];
  float* out = (float*)d_out;

  unsigned char* base = nullptr;
  if (ws_size >= TOTAL_BYTES) {
    base = (unsigned char*)d_ws;
  } else {
    hipGetSymbolAddress((void**)&base, HIP_SYMBOL(g_buf));
  }
  bf16* bb = (bf16*)base;
  bf16* wt_attn = bb + E_WT_ATTN;
  bf16* wt_proj = bb + E_WT_PROJ;
  bf16* wt_mlp1 = bb + E_WT_MLP1;
  bf16* wt_mlp2 = bb + E_WT_MLP2;
  bf16* ln1o = bb + E_LN1;
  bf16* qkv = bb + E_QKV;
  bf16* vTb = bb + E_VT;
  bf16* yb = bb + E_Y;
  bf16* ln2o = bb + E_LN2;
  bf16* hb = bb + E_H;
  float* x2 = (float*)(base + BYTE_X2);
  float* o_part = (float*)(base + BYTE_OPART);
  float* ml_part = (float*)(base + BYTE_ML);
  float* gpart = (float*)(base + BYTE_GPART);

  transpose_all<<<12288, dim3(32, 8), 0, stream>>>(attn_w, proj_w, mlp_w1, mlp_w2,
                                                   wt_attn, wt_proj, wt_mlp1, wt_mlp2);

  ln_bf16<<<4096, 256, 0, stream>>>(x, ln1_g, ln1_b, ln1o);

  gemm256<0><<<dim3(12, 16, 1), 512, 0, stream>>>(ln1o, wt_attn, attn_b, qkv, nullptr,
                                                  4096, 3072, 1024, 1024);

  split_v_t<<<dim3(64, 32), 256, 0, stream>>>(qkv, vTb);

  attn_fwd<<<2048, 256, 0, stream>>>(qkv, vTb, o_part, ml_part);
  attn_combine<<<1024, 256, 0, stream>>>(o_part, ml_part, yb);

  gemm_bt3<<<dim3(8, 32, 2), 256, 0, stream>>>(yb, wt_proj, gpart, 4096, 1024, 1024, 512);
  reduce_ln<<<4096, 256, 0, stream>>>(gpart, proj_b, x, w_att, ln2_g, ln2_b, x2, ln2o);

  gemm256<1><<<dim3(16, 16, 1), 512, 0, stream>>>(ln2o, wt_mlp1, mlp_b1, hb, nullptr,
                                                  4096, 4096, 1024, 1024);

  gemm256<3><<<dim3(4, 16, 4), 512, 0, stream>>>(hb, wt_mlp2, nullptr, nullptr, gpart,
                                                 4096, 1024, 4096, 1024);
  reduce_add<4><<<4096, 256, 0, stream>>>(gpart, mlp_b2, x2, w_mlp, out, 4194304, 1024);
}